// Round 9
// baseline (347.600 us; speedup 1.0000x reference)
//
#include <hip/hip_runtime.h>
#include <math.h>

// GCN via CSR gather. CSR(dst) built with a two-level binned counting sort where
// node degrees are derived INSIDE the partition sort (lsortA LDS histogram).
// 3x (MFMA GEMM -> gather-agg[+relu,bf16]) -> mean-pool -> head -> softmax.
//
// NOTE (round 5/6 counters): top-5 incl. __amd_rocclr_fillBufferAligned x4/iter,
// ~41us each, 256MiB at 82% HBM peak = harness workspace re-poison counted in
// dur_us, already at roofline -> ~164us fixed tax. Addressable budget ~180us.
//
// Round 9 (this round): bin_gemm was 45us with EVERYTHING idle (VALU 5.6%,
// HBM 16%, Mfma 1.2%) -> un-overlapped latency chain. Culprit: bin inner loop
// {load dst/src -> LDS atomicAdd -> store}, 1 edge/thread/iter x24; the atomic
// depends on the load AND blocks hoisting next iter's loads -> ~900cy exposed
// per iteration. FIX: batch 8 contiguous edges/thread/pass -- issue 8+8 loads
// as int4 pairs up front, then 8x{atomic,store}. Latency paid once per 8 edges
// (serial chain 24x900 -> 3x900). C rounded to multiple of 8 (6256) so every
// group is 16B-aligned; E,C =0 mod 8 -> no scalar tail (guard kept for safety).
//
// Round 8: restored precomputed offs (round-7's self-computed offsets were a
// 64-line uncoalesced load x255 iters -> 54us); kept bin||gemm1 block-range
// fusion (blocks [0,256)=bin, [256,..)=gemm1, disjoint memory).
// Gather v9 (round 6): FIXED-STRIDE CSR, 24 slots/node at csrw[node*24]
// (deg<=23 = 96.3% of Poisson(16), self-loop included, weight-0 pads),
// overflow via packed ovfw[node]. beg pure VALU, no rowptr, straight gstep<3>.
// Per round-6 decision rule (gather >=35us): random-row L2-miss throughput
// wall (~90MB @ ~2.4TB/s); latency levers exhausted.
// Gather v8 (round 5): merged remainder gstep<nb>, f32x2 pk_fma. Pool v2
// (round 4): wave/32 nodes, batch __shfl, 32 row loads upfront. GEMM v3
// (round 4): LDS-staged X, MFMA 16x16x32. 64.4->47.5->45.2->42.9->~38->~36us.
// N=100000 nodes, E=1.6M edges, nhid=64, Poisson(16) degrees.

typedef __attribute__((ext_vector_type(8))) short bf16x8;
typedef __attribute__((ext_vector_type(4))) float f32x4;
typedef __attribute__((ext_vector_type(2))) float f32x2;

__device__ __forceinline__ unsigned short f2bf(float f) {
    unsigned int u = __float_as_uint(f);
    u += 0x7fffu + ((u >> 16) & 1u);   // round-to-nearest-even
    return (unsigned short)(u >> 16);
}
__device__ __forceinline__ float bf2f(unsigned short u) {
    return __uint_as_float((unsigned int)u << 16);
}
__device__ __forceinline__ float bflo(unsigned int u) {
    return __uint_as_float(u << 16);
}
__device__ __forceinline__ float bfhi(unsigned int u) {
    return __uint_as_float(u & 0xffff0000u);
}

// ---- binned counting sort: partition = dst>>9 (512 nodes), P<=256, 256 chunks ----
// hist fused: blocks 256..258 = W->Wt bf16 transpose; block 259 = zero sums/cnts.

__global__ __launch_bounds__(256) void hist_kernel(const int* __restrict__ dst,
                                                   int* __restrict__ counts,
                                                   int E, int P, int C,
                                                   const float* __restrict__ W1,
                                                   const float* __restrict__ W2,
                                                   const float* __restrict__ W3,
                                                   unsigned short* __restrict__ Wt1,
                                                   unsigned short* __restrict__ Wt2,
                                                   unsigned short* __restrict__ Wt3,
                                                   float* __restrict__ sums, int G) {
    int t = threadIdx.x, b = blockIdx.x;
    if (b >= 256) {
        int xb = b - 256;
        if (xb < 3) {           // prepw
            const float* W = (xb == 0) ? W1 : ((xb == 1) ? W2 : W3);
            unsigned short* Wt = (xb == 0) ? Wt1 : ((xb == 1) ? Wt2 : Wt3);
            int K = (xb == 0) ? 128 : 64;
            int o = t & 63;
            for (int k = t >> 6; k < K; k += 4)
                Wt[o * K + k] = f2bf(W[k * 64 + o]);
        } else {                // zero sums+cnts (G*65 floats)
            for (int i = t; i < G * 65; i += 256) sums[i] = 0.f;
        }
        return;
    }
    __shared__ int hist[256];
    if (t < P) hist[t] = 0;
    __syncthreads();
    int beg = b * C, end = min(E, beg + C);
    for (int e = beg + t; e < end; e += 256)
        atomicAdd(&hist[dst[e] >> 9], 1);
    __syncthreads();
    if (t < P) counts[t * 256 + b] = hist[t];
}

__global__ __launch_bounds__(256) void pscan_kernel(const int* __restrict__ counts,
                                                    int* __restrict__ pbase,
                                                    int P) {
    __shared__ int s[256];
    int t = threadIdx.x;
    int v = 0;
    if (t < P)
        for (int b = 0; b < 256; ++b) v += counts[t * 256 + b];
    s[t] = v;
    __syncthreads();
    for (int off = 1; off < 256; off <<= 1) {
        int u = (t >= off) ? s[t - off] : 0;
        __syncthreads();
        s[t] += u;
        __syncthreads();
    }
    if (t < P) pbase[t] = s[t] - v;
    if (t == 255) pbase[P] = s[255];
}

// Per-partition chunk-offset table: offs[p*256+t] = pbase[p] + prefix of
// counts[p*256+*] over chunks < t. Coalesced LDS scan, P blocks, ~3us.
__global__ __launch_bounds__(256) void offs_kernel(const int* __restrict__ counts,
                                                   const int* __restrict__ pbase,
                                                   int* __restrict__ offs) {
    __shared__ int s[256];
    int t = threadIdx.x, p = blockIdx.x;
    int v = counts[p * 256 + t];
    s[t] = v;
    __syncthreads();
    for (int off = 1; off < 256; off <<= 1) {
        int u = (t >= off) ? s[t - off] : 0;
        __syncthreads();
        s[t] += u;
        __syncthreads();
    }
    offs[p * 256 + t] = pbase[p] + s[t] - v;
}

// Fused: blocks [0,256) = bin scatter (precomputed offs, 8-edge batched loads);
// blocks [256, 256+gemmGrid) = gemm1 (H = bf16(X[N,128] @ W1), MFMA, LDS-staged).
// Disjoint memory: bin writes binned (aggb slot), gemm writes h. Concurrent.
__global__ __launch_bounds__(256) void bin_gemm_kernel(const int* __restrict__ src,
                                                       const int* __restrict__ dst,
                                                       const int* __restrict__ offs,
                                                       unsigned int* __restrict__ binned,
                                                       int E, int P, int C,
                                                       const float* __restrict__ X,
                                                       const unsigned short* __restrict__ Wt,
                                                       unsigned short* __restrict__ H, int N) {
    __shared__ int cur[256];
    __shared__ unsigned short sX[64 * 136];   // gemm path: LDP = 128+8
    int t = threadIdx.x, b = blockIdx.x;

    if (b < 256) {
        // ---- bin path: 8 contiguous edges per thread per pass, loads batched
        // up front (int4 pairs, 16B-aligned since C%8==0) so the load latency
        // is paid once per 8 edges, not once per edge (round-9 fix).
        if (t < P) cur[t] = offs[t * 256 + b];
        __syncthreads();
        int beg = b * C, end = min(E, beg + C);
        for (int base = beg + t * 8; base < end; base += 2048) {
            if (base + 8 <= end) {
                int4 d0 = *(const int4*)&dst[base];
                int4 d1 = *(const int4*)&dst[base + 4];
                int4 s0 = *(const int4*)&src[base];
                int4 s1 = *(const int4*)&src[base + 4];
                int d[8] = {d0.x, d0.y, d0.z, d0.w, d1.x, d1.y, d1.z, d1.w};
                int s[8] = {s0.x, s0.y, s0.z, s0.w, s1.x, s1.y, s1.z, s1.w};
#pragma unroll
                for (int j = 0; j < 8; ++j) {
                    int pos = atomicAdd(&cur[d[j] >> 9], 1);
                    binned[pos] = ((unsigned int)s[j] << 9) | (unsigned int)(d[j] & 511);
                }
            } else {
                for (int e = base; e < end; ++e) {
                    int dd = dst[e], ss = src[e];
                    int pos = atomicAdd(&cur[dd >> 9], 1);
                    binned[pos] = ((unsigned int)ss << 9) | (unsigned int)(dd & 511);
                }
            }
        }
        return;
    }

    // ---- gemm1 path (FIN=128, fp32 input) ----
    constexpr int FIN = 128;
    constexpr int KS = FIN / 32;
    constexpr int LDP = FIN + 8;
    int rowBase = (b - 256) * 64;

    for (int i = t * 4; i < 64 * FIN; i += 1024) {
        int r = i / FIN, c = i - r * FIN;
        int gr = min(rowBase + r, N - 1);
        float4 vv = *(const float4*)(X + (size_t)gr * FIN + c);
        unsigned e0 = __float_as_uint(vv.x) + 0x8000u, e1 = __float_as_uint(vv.y) + 0x8000u;
        unsigned e2 = __float_as_uint(vv.z) + 0x8000u, e3 = __float_as_uint(vv.w) + 0x8000u;
        uint2 pk;
        pk.x = __builtin_amdgcn_perm(e1, e0, 0x07060302);
        pk.y = __builtin_amdgcn_perm(e3, e2, 0x07060302);
        *(uint2*)&sX[r * LDP + c] = pk;
    }
    __syncthreads();

    int wave = t >> 6;
    int lane = t & 63;
    int r = lane & 15, g = lane >> 4;
    int node = rowBase + wave * 16 + r;

    bf16x8 afr[4][KS];
#pragma unroll
    for (int m = 0; m < 4; ++m)
#pragma unroll
        for (int s = 0; s < KS; ++s)
            afr[m][s] = *(const bf16x8*)&Wt[(m * 16 + r) * FIN + s * 32 + g * 8];

    f32x4 acc[4];
#pragma unroll
    for (int m = 0; m < 4; ++m) acc[m] = (f32x4){0.f, 0.f, 0.f, 0.f};

#pragma unroll
    for (int s = 0; s < KS; ++s) {
        bf16x8 bfr = *(const bf16x8*)&sX[(wave * 16 + r) * LDP + s * 32 + g * 8];
#pragma unroll
        for (int m = 0; m < 4; ++m)
            acc[m] = __builtin_amdgcn_mfma_f32_16x16x32_bf16(afr[m][s], bfr, acc[m], 0, 0, 0);
    }

    if (node < N) {
#pragma unroll
        for (int m = 0; m < 4; ++m) {
            ushort4 o;
            o.x = f2bf(acc[m][0]); o.y = f2bf(acc[m][1]);
            o.z = f2bf(acc[m][2]); o.w = f2bf(acc[m][3]);
            *(ushort4*)&H[(size_t)node * 64 + m * 16 + g * 4] = o;
        }
    }
}

// Per-node degree (LDS histogram) -> dinv + overflow allocation. Overflow region
// for node with deg1 = deg+1 > 24: gsl = align8(deg1-24) slots, allocated at
// per-partition fixed base align8(pbase[p]) + 4096p + localScan. ovfw[node] =
// (slotBase/8)<<7 | (gsl/8), or 0 if no overflow. NO cross-partition scan.
__global__ __launch_bounds__(512) void lsortA_kernel(const unsigned int* __restrict__ binned,
                                                     const int* __restrict__ pbase,
                                                     float* __restrict__ dinv,
                                                     int* __restrict__ ovfw, int N) {
    __shared__ int ldeg[512];
    __shared__ int s[512];
    int t = threadIdx.x, p = blockIdx.x;
    int lo = p << 9;
    ldeg[t] = 0;
    __syncthreads();
    int eBeg = pbase[p], eEnd = pbase[p + 1];
    for (int j = eBeg + t; j < eEnd; j += 512)
        atomicAdd(&ldeg[binned[j] & 511u], 1);
    __syncthreads();
    int real = ldeg[t];
    int deg1 = real + 1;
    int ovfUsed = (lo + t < N) ? max(deg1 - 24, 0) : 0;
    int gsl = ((ovfUsed + 7) >> 3) << 3;       // padded ovf slots (multiple of 8)
    s[t] = gsl;
    __syncthreads();
    for (int off = 1; off < 512; off <<= 1) {
        int u = (t >= off) ? s[t - off] : 0;
        __syncthreads();
        s[t] += u;
        __syncthreads();
    }
    if (lo + t < N) {
        dinv[lo + t] = rsqrtf((float)deg1);
        int obase = ((eBeg + 7) & ~7) + (p << 12);       // align8(pbase[p]) + 4096p
        int base = obase + (s[t] - gsl);                 // exclusive local scan
        ovfw[lo + t] = gsl ? (((base >> 3) << 7) | (gsl >> 3)) : 0;
    }
}

// Scatter: entry i (arrival order; self appended last) -> i<24: csrw[node*24+i],
// else ovf[base + i-24]. Then pads {0,0} in main tail and ovf tail.
__global__ __launch_bounds__(256) void lsortB_kernel(const unsigned int* __restrict__ binned,
                                                     const int* __restrict__ pbase,
                                                     const int* __restrict__ ovfw,
                                                     const float* __restrict__ dinv,
                                                     float2* __restrict__ csrw,
                                                     float2* __restrict__ ovf, int N) {
    __shared__ int cur[512];
    __shared__ float sdi[512];
    __shared__ int sov[512];
    int t = threadIdx.x, p = blockIdx.x;
    int lo = p << 9, span = min(N - lo, 512);
    for (int i = t; i < span; i += 256) {
        cur[i] = 0;
        sdi[i] = dinv[lo + i];
        sov[i] = ovfw[lo + i];
    }
    __syncthreads();
    int eBeg = pbase[p], eEnd = pbase[p + 1];
    for (int j = eBeg + t; j < eEnd; j += 256) {
        unsigned int vv = binned[j];
        int sr = (int)(vv >> 9);
        int dl = (int)(vv & 511u);
        int i = atomicAdd(&cur[dl], 1);
        float2 ent = make_float2(__int_as_float(sr << 7), dinv[sr] * sdi[dl]);
        if (i < 24) csrw[(size_t)(lo + dl) * 24 + i] = ent;
        else        ovf[(size_t)((sov[dl] >> 7) << 3) + i - 24] = ent;
    }
    __syncthreads();
    for (int i = t; i < span; i += 256) {
        int real = cur[i];
        int node = lo + i;
        float d = sdi[i];
        float2 self = make_float2(__int_as_float(node << 7), d * d);
        int deg1 = real + 1;
        int ob = (sov[i] >> 7) << 3;
        if (real < 24) csrw[(size_t)node * 24 + real] = self;
        else           ovf[(size_t)ob + real - 24] = self;
        for (int k = deg1; k < 24; ++k)
            csrw[(size_t)node * 24 + k] = make_float2(0.f, 0.f);     // main pads
        int gsl = (sov[i] & 127) << 3;
        for (int k = max(deg1 - 24, 0); k < gsl; ++k)
            ovf[(size_t)ob + k] = make_float2(0.f, 0.f);             // ovf pads
    }
}

// MFMA GEMM v3 (layers 2/3, bf16 input): H[N,64](bf16) = X[N,64] @ W[64,64].
// X tile staged through LDS (coalesced), fragments via ds_read_b128.
template <int FIN>
__global__ __launch_bounds__(256) void gemm_mfma_kernel(const unsigned short* __restrict__ Xv,
                                                        const unsigned short* __restrict__ Wt,
                                                        unsigned short* __restrict__ H,
                                                        int N) {
    constexpr int KS = FIN / 32;
    constexpr int LDP = FIN + 8;
    __shared__ unsigned short sX[64 * LDP];
    int tid = threadIdx.x;
    int rowBase = blockIdx.x * 64;

    for (int i = tid * 8; i < 64 * FIN; i += 2048) {
        int r = i / FIN, c = i - r * FIN;
        int gr = min(rowBase + r, N - 1);
        uint4 vv = *(const uint4*)(Xv + (size_t)gr * FIN + c);
        *(uint4*)&sX[r * LDP + c] = vv;
    }
    __syncthreads();

    int wave = tid >> 6;
    int lane = tid & 63;
    int r = lane & 15, g = lane >> 4;
    int node = rowBase + wave * 16 + r;

    bf16x8 afr[4][KS];
#pragma unroll
    for (int m = 0; m < 4; ++m)
#pragma unroll
        for (int s = 0; s < KS; ++s)
            afr[m][s] = *(const bf16x8*)&Wt[(m * 16 + r) * FIN + s * 32 + g * 8];

    f32x4 acc[4];
#pragma unroll
    for (int m = 0; m < 4; ++m) acc[m] = (f32x4){0.f, 0.f, 0.f, 0.f};

#pragma unroll
    for (int s = 0; s < KS; ++s) {
        bf16x8 bfr = *(const bf16x8*)&sX[(wave * 16 + r) * LDP + s * 32 + g * 8];
#pragma unroll
        for (int m = 0; m < 4; ++m)
            acc[m] = __builtin_amdgcn_mfma_f32_16x16x32_bf16(afr[m][s], bfr, acc[m], 0, 0, 0);
    }

    if (node < N) {
#pragma unroll
        for (int m = 0; m < 4; ++m) {
            ushort4 o;
            o.x = f2bf(acc[m][0]); o.y = f2bf(acc[m][1]);
            o.z = f2bf(acc[m][2]); o.w = f2bf(acc[m][3]);
            *(ushort4*)&H[(size_t)node * 64 + m * 16 + g * 4] = o;
        }
    }
}

// Gather step: NQ x 8 edges, unguarded (slots 8-aligned, pads weight 0).
template <int NQ>
__device__ __forceinline__ void gstep(const float2* __restrict__ csrw,
                                      const char* __restrict__ hb,
                                      int e, int g, int fo, f32x2 acc[4]) {
    float2 c[NQ];
#pragma unroll
    for (int q = 0; q < NQ; ++q) c[q] = csrw[e + 8 * q + g];
    uint4 u[NQ];
#pragma unroll
    for (int q = 0; q < NQ; ++q)
        u[q] = *(const uint4*)(hb + __float_as_int(c[q].x) + fo);
#pragma unroll
    for (int q = 0; q < NQ; ++q) {
        f32x2 w2;
        w2.x = c[q].y; w2.y = c[q].y;
        acc[0] = __builtin_elementwise_fma(w2, (f32x2){bflo(u[q].x), bfhi(u[q].x)}, acc[0]);
        acc[1] = __builtin_elementwise_fma(w2, (f32x2){bflo(u[q].y), bfhi(u[q].y)}, acc[1]);
        acc[2] = __builtin_elementwise_fma(w2, (f32x2){bflo(u[q].z), bfhi(u[q].z)}, acc[2]);
        acc[3] = __builtin_elementwise_fma(w2, (f32x2){bflo(u[q].w), bfhi(u[q].w)}, acc[3]);
    }
}

// Gather v9: one wave per dst node. lane j: edge-slot g=j>>3, feat f=j&7.
// Fixed-stride CSR: 24 slots at csrw[node*24]; overflow via packed ovfw.
__global__ __launch_bounds__(256) void gather_kernel(const float2* __restrict__ csrw,
                                                     const float2* __restrict__ ovf,
                                                     const int* __restrict__ ovfw,
                                                     const unsigned short* __restrict__ h,
                                                     const float* __restrict__ b,
                                                     unsigned short* __restrict__ aggb, int N) {
    int node = (blockIdx.x * 256 + threadIdx.x) >> 6;
    int lane = threadIdx.x & 63;
    if (node >= N) return;
    int g = lane >> 3;
    int f = lane & 7;
    int fo = f * 16;

    f32x2 acc[4];
#pragma unroll
    for (int k = 0; k < 4; ++k) acc[k] = (f32x2){0.f, 0.f};

    const char* hb = (const char*)h;
    gstep<3>(csrw, hb, node * 24, g, fo, acc);

    int ow = ovfw[node];
    if (ow) {
        int onb = ow & 127;
        int oe = (ow >> 7) << 3;
        while (onb >= 4) { gstep<4>(ovf, hb, oe, g, fo, acc); oe += 32; onb -= 4; }
        if (onb == 3)      gstep<3>(ovf, hb, oe, g, fo, acc);
        else if (onb == 2) gstep<2>(ovf, hb, oe, g, fo, acc);
        else if (onb == 1) gstep<1>(ovf, hb, oe, g, fo, acc);
    }

    float a[8];
#pragma unroll
    for (int k = 0; k < 4; ++k) { a[2 * k] = acc[k].x; a[2 * k + 1] = acc[k].y; }
#pragma unroll
    for (int k = 0; k < 8; ++k) {
        float v = a[k];
        v += __shfl_xor(v, 8);
        v += __shfl_xor(v, 16);
        v += __shfl_xor(v, 32);
        a[k] = v;
    }
    if (g == 0) {
        float4 bv0 = *(const float4*)&b[f * 8];
        float4 bv1 = *(const float4*)&b[f * 8 + 4];
        float a0 = fmaxf(a[0] + bv0.x, 0.f), a1 = fmaxf(a[1] + bv0.y, 0.f);
        float a2 = fmaxf(a[2] + bv0.z, 0.f), a3 = fmaxf(a[3] + bv0.w, 0.f);
        float a4 = fmaxf(a[4] + bv1.x, 0.f), a5 = fmaxf(a[5] + bv1.y, 0.f);
        float a6 = fmaxf(a[6] + bv1.z, 0.f), a7 = fmaxf(a[7] + bv1.w, 0.f);
        uint4 o;
        o.x = ((unsigned)f2bf(a1) << 16) | f2bf(a0);
        o.y = ((unsigned)f2bf(a3) << 16) | f2bf(a2);
        o.z = ((unsigned)f2bf(a5) << 16) | f2bf(a4);
        o.w = ((unsigned)f2bf(a7) << 16) | f2bf(a6);
        *(uint4*)&aggb[((size_t)node << 6) + f * 8] = o;
    }
}

// Pool v2: one wave per 32 contiguous nodes (lane = col). batch preloaded once
// (coalesced) + __shfl per node; all 32 row loads issued upfront.
__global__ __launch_bounds__(256) void pool_kernel(const unsigned short* __restrict__ hb,
                                                   const int* __restrict__ batch,
                                                   float* __restrict__ sums,
                                                   float* __restrict__ cnts, int N) {
    int lane = threadIdx.x & 63;
    int wid = (blockIdx.x * 256 + threadIdx.x) >> 6;
    int base = wid * 32;
    if (base >= N) return;
    int nn = min(N - base, 32);
    int bl = batch[base + min(lane & 31, nn - 1)];

    float v[32];
#pragma unroll
    for (int j = 0; j < 32; ++j) {
        int node = base + min(j, nn - 1);
        v[j] = bf2f(hb[(size_t)node * 64 + lane]);
    }

    int curg = __shfl(bl, 0);
    float acc = 0.f, cnt = 0.f;
#pragma unroll
    for (int j = 0; j < 32; ++j) {
        if (j < nn) {
            int g = __shfl(bl, j);
            if (g != curg) {
                atomicAdd(&sums[curg * 64 + lane], acc);
                if (lane == 0) atomicAdd(&cnts[curg], cnt);
                acc = 0.f; cnt = 0.f; curg = g;
            }
            acc += v[j]; cnt += 1.f;
        }
    }
    atomicAdd(&sums[curg * 64 + lane], acc);
    if (lane == 0) atomicAdd(&cnts[curg], cnt);
}

// One thread per graph: pooled = sums/cnt, logits = pooled @ Wl + bl, softmax.
__global__ void final_kernel(const float* __restrict__ sums, const float* __restrict__ cnts,
                             const float* __restrict__ Wl, const float* __restrict__ bl,
                             float* __restrict__ out, int G) {
    int g = blockIdx.x * blockDim.x + threadIdx.x;
    if (g >= G) return;
    float inv = 1.0f / fmaxf(cnts[g], 1.0f);
    float logits[10];
#pragma unroll
    for (int k = 0; k < 10; ++k) logits[k] = bl[k];
    for (int c = 0; c < 64; ++c) {
        float p = sums[g * 64 + c] * inv;
#pragma unroll
        for (int k = 0; k < 10; ++k) logits[k] = fmaf(p, Wl[c * 10 + k], logits[k]);
    }
    float m = logits[0];
#pragma unroll
    for (int k = 1; k < 10; ++k) m = fmaxf(m, logits[k]);
    float se = 0.f;
#pragma unroll
    for (int k = 0; k < 10; ++k) { logits[k] = expf(logits[k] - m); se += logits[k]; }
    float is = 1.0f / se;
#pragma unroll
    for (int k = 0; k < 10; ++k) out[g * 10 + k] = logits[k] * is;
}

extern "C" void kernel_launch(void* const* d_in, const int* in_sizes, int n_in,
                              void* d_out, int out_size, void* d_ws, size_t ws_size,
                              hipStream_t stream) {
    const float* x    = (const float*)d_in[0];
    const int* edges  = (const int*)d_in[1];
    const int* batch  = (const int*)d_in[2];
    const float* W1   = (const float*)d_in[3];
    const float* b1   = (const float*)d_in[4];
    const float* W2   = (const float*)d_in[5];
    const float* b2   = (const float*)d_in[6];
    const float* W3   = (const float*)d_in[7];
    const float* b3   = (const float*)d_in[8];
    const float* Wl   = (const float*)d_in[9];
    const float* bl   = (const float*)d_in[10];

    const int N = in_sizes[0] / 128;   // 100000
    const int E = in_sizes[1] / 2;     // 1600000
    const int G = out_size / 10;       // 64
    const int* src = edges;
    const int* dst = edges + E;

    // workspace layout (floats).
    float* ws     = (float*)d_ws;
    unsigned short* h = (unsigned short*)ws;              // N*64 bf16 = N*32 floats
    unsigned short* aggb = (unsigned short*)(ws + (size_t)N * 32);  // N*64 bf16
    unsigned int* binned = (unsigned int*)(ws + (size_t)N * 32);    // E uint, ALIASES aggb
                                                          // (dead until gather1; h is free
                                                          // for gemm1 concurrent with bin)
    size_t o = (size_t)N * 64;
    float2* csrw  = (float2*)(ws + o);  o += (size_t)48 * N;          // 24N float2
    float2* ovf   = (float2*)(ws + o);  o += (size_t)2 * (E + 4096 * 256 + 8);
    float* dinv   = ws + o;            o += N;
    int*   ovfw   = (int*)(ws + o);    o += N;
    int*   counts = (int*)(ws + o);    o += 256 * 256;
    int*   offs   = (int*)(ws + o);    o += 256 * 256;
    int*   pbase  = (int*)(ws + o);    o += 257;
    float* sums   = ws + o;            o += (size_t)G * 64;
    float* cnts   = ws + o;            o += G;
    unsigned short* Wt1 = (unsigned short*)(ws + o);      // 64*128 + 2*64*64 shorts
    unsigned short* Wt2 = Wt1 + 64 * 128;
    unsigned short* Wt3 = Wt2 + 64 * 64;

    const int gemmGrid = (N + 63) / 64;
    const int gatherGrid = (N + 3) / 4;
    const int poolGrid = ((N + 31) / 32 + 3) / 4;
    const int P = (N + 511) >> 9;                 // 196 partitions of 512 nodes
    const int C = (((E + 255) / 256) + 7) & ~7;   // edges per chunk, multiple of 8
                                                  // (16B-aligned int4 batches in bin)

    // sort -> fixed-stride CSR (24 slots/node) + overflow region
    hist_kernel<<<260, 256, 0, stream>>>(dst, counts, E, P, C,
                                         W1, W2, W3, Wt1, Wt2, Wt3, sums, G);
    pscan_kernel<<<1, 256, 0, stream>>>(counts, pbase, P);
    offs_kernel<<<P, 256, 0, stream>>>(counts, pbase, offs);
    // fused: bin (blocks 0..255, batched loads) || gemm1 (blocks 256..)
    bin_gemm_kernel<<<256 + gemmGrid, 256, 0, stream>>>(src, dst, offs,
                                                        binned, E, P, C,
                                                        x, Wt1, h, N);
    lsortA_kernel<<<P, 512, 0, stream>>>(binned, pbase, dinv, ovfw, N);
    lsortB_kernel<<<P, 256, 0, stream>>>(binned, pbase, ovfw, dinv, csrw, ovf, N);

    // layer 1 gather (h ready since bin_gemm; csrw ready since lsortB)
    gather_kernel<<<gatherGrid, 256, 0, stream>>>(csrw, ovf, ovfw, h, b1, aggb, N);

    // layer 2
    gemm_mfma_kernel<64><<<gemmGrid, 256, 0, stream>>>(aggb, Wt2, h, N);
    gather_kernel<<<gatherGrid, 256, 0, stream>>>(csrw, ovf, ovfw, h, b2, aggb, N);

    // layer 3
    gemm_mfma_kernel<64><<<gemmGrid, 256, 0, stream>>>(aggb, Wt3, h, N);
    gather_kernel<<<gatherGrid, 256, 0, stream>>>(csrw, ovf, ovfw, h, b3, aggb, N);

    // mean-pool per graph + head + softmax (sums/cnts zeroed in hist's extra block)
    pool_kernel<<<poolGrid, 256, 0, stream>>>(aggb, batch, sums, cnts, N);
    final_kernel<<<1, 64, 0, stream>>>(sums, cnts, Wl, bl, (float*)d_out, G);
}

// Round 10
// 343.816 us; speedup vs baseline: 1.0110x; 1.0110x over previous
//
#include <hip/hip_runtime.h>
#include <math.h>

// GCN via CSR gather. CSR(dst) built with a two-level binned counting sort where
// node degrees are derived INSIDE the partition sort (lsortA LDS histogram).
// 3x (MFMA GEMM -> gather-agg[+relu,bf16]) -> mean-pool -> head -> softmax.
//
// NOTE: top-5 incl. __amd_rocclr_fillBufferAligned x4/iter, ~41us each, 256MiB
// at 82% HBM peak = harness workspace re-poison counted in dur_us, at roofline
// -> ~165us fixed tax. Addressable budget ~180us.
//
// Round 10 (this round): ISOLATION. Rounds 7-9 fused bin||gemm1; the fused
// dispatch stuck at 42-45us with ALL pipes idle, and neither path's model
// (bin batched ~3us, gemm1 ~13us) explains it. Round-6 arithmetic (unfused
// bin+gemm ~49us serial vs fused 45) says one path was ~35-40us STANDALONE and
// we never measured which. Un-fuse (keep batched bin loads) -> direct counters
// per kernel. Candidate mechanism if gemm1 is slow: the 256MB fill leaves L3
// fully dirty, so the 51MB x read pays writeback+read per miss (~1.3TB/s eff).
//
// Round 9: bin loads batched 8 edges/thread (int4 pairs up front) -> latency
// paid once per 8 edges. C rounded to multiple of 8 for 16B alignment.
// Round 8: precomputed offs (round-7's self-computed offsets = 64-line
// uncoalesced load x255 -> 54us regression, reverted).
// Gather v9 (round 6): FIXED-STRIDE CSR, 24 slots/node at csrw[node*24]
// (deg<=23 = 96.3% of Poisson(16), self-loop included, weight-0 pads),
// overflow via packed ovfw[node]. Random-row L2-miss wall ~36us/dispatch.
// Gather v8 (round 5): merged remainder gstep<nb>, f32x2 pk_fma. Pool v2
// (round 4): wave/32 nodes, batch __shfl, 32 row loads upfront. GEMM v3
// (round 4): LDS-staged X, MFMA 16x16x32.
// N=100000 nodes, E=1.6M edges, nhid=64, Poisson(16) degrees.

typedef __attribute__((ext_vector_type(8))) short bf16x8;
typedef __attribute__((ext_vector_type(4))) float f32x4;
typedef __attribute__((ext_vector_type(2))) float f32x2;

__device__ __forceinline__ unsigned short f2bf(float f) {
    unsigned int u = __float_as_uint(f);
    u += 0x7fffu + ((u >> 16) & 1u);   // round-to-nearest-even
    return (unsigned short)(u >> 16);
}
__device__ __forceinline__ float bf2f(unsigned short u) {
    return __uint_as_float((unsigned int)u << 16);
}
__device__ __forceinline__ float bflo(unsigned int u) {
    return __uint_as_float(u << 16);
}
__device__ __forceinline__ float bfhi(unsigned int u) {
    return __uint_as_float(u & 0xffff0000u);
}

// ---- binned counting sort: partition = dst>>9 (512 nodes), P<=256, 256 chunks ----
// hist fused: blocks 256..258 = W->Wt bf16 transpose; block 259 = zero sums/cnts.

__global__ __launch_bounds__(256) void hist_kernel(const int* __restrict__ dst,
                                                   int* __restrict__ counts,
                                                   int E, int P, int C,
                                                   const float* __restrict__ W1,
                                                   const float* __restrict__ W2,
                                                   const float* __restrict__ W3,
                                                   unsigned short* __restrict__ Wt1,
                                                   unsigned short* __restrict__ Wt2,
                                                   unsigned short* __restrict__ Wt3,
                                                   float* __restrict__ sums, int G) {
    int t = threadIdx.x, b = blockIdx.x;
    if (b >= 256) {
        int xb = b - 256;
        if (xb < 3) {           // prepw
            const float* W = (xb == 0) ? W1 : ((xb == 1) ? W2 : W3);
            unsigned short* Wt = (xb == 0) ? Wt1 : ((xb == 1) ? Wt2 : Wt3);
            int K = (xb == 0) ? 128 : 64;
            int o = t & 63;
            for (int k = t >> 6; k < K; k += 4)
                Wt[o * K + k] = f2bf(W[k * 64 + o]);
        } else {                // zero sums+cnts (G*65 floats)
            for (int i = t; i < G * 65; i += 256) sums[i] = 0.f;
        }
        return;
    }
    __shared__ int hist[256];
    if (t < P) hist[t] = 0;
    __syncthreads();
    int beg = b * C, end = min(E, beg + C);
    for (int e = beg + t; e < end; e += 256)
        atomicAdd(&hist[dst[e] >> 9], 1);
    __syncthreads();
    if (t < P) counts[t * 256 + b] = hist[t];
}

__global__ __launch_bounds__(256) void pscan_kernel(const int* __restrict__ counts,
                                                    int* __restrict__ pbase,
                                                    int P) {
    __shared__ int s[256];
    int t = threadIdx.x;
    int v = 0;
    if (t < P)
        for (int b = 0; b < 256; ++b) v += counts[t * 256 + b];
    s[t] = v;
    __syncthreads();
    for (int off = 1; off < 256; off <<= 1) {
        int u = (t >= off) ? s[t - off] : 0;
        __syncthreads();
        s[t] += u;
        __syncthreads();
    }
    if (t < P) pbase[t] = s[t] - v;
    if (t == 255) pbase[P] = s[255];
}

// Per-partition chunk-offset table: offs[p*256+t] = pbase[p] + prefix of
// counts[p*256+*] over chunks < t. Coalesced LDS scan, P blocks, ~3us.
__global__ __launch_bounds__(256) void offs_kernel(const int* __restrict__ counts,
                                                   const int* __restrict__ pbase,
                                                   int* __restrict__ offs) {
    __shared__ int s[256];
    int t = threadIdx.x, p = blockIdx.x;
    int v = counts[p * 256 + t];
    s[t] = v;
    __syncthreads();
    for (int off = 1; off < 256; off <<= 1) {
        int u = (t >= off) ? s[t - off] : 0;
        __syncthreads();
        s[t] += u;
        __syncthreads();
    }
    offs[p * 256 + t] = pbase[p] + s[t] - v;
}

// bin scatter, STANDALONE (round-10 un-fuse for direct counters). 8 contiguous
// edges per thread per pass; int4-pair loads issued up front (16B-aligned,
// C%8==0) so load latency is paid once per 8 edges.
__global__ __launch_bounds__(256) void bin_kernel(const int* __restrict__ src,
                                                  const int* __restrict__ dst,
                                                  const int* __restrict__ offs,
                                                  unsigned int* __restrict__ binned,
                                                  int E, int P, int C) {
    __shared__ int cur[256];
    int t = threadIdx.x, b = blockIdx.x;
    if (t < P) cur[t] = offs[t * 256 + b];
    __syncthreads();
    int beg = b * C, end = min(E, beg + C);
    for (int base = beg + t * 8; base < end; base += 2048) {
        if (base + 8 <= end) {
            int4 d0 = *(const int4*)&dst[base];
            int4 d1 = *(const int4*)&dst[base + 4];
            int4 s0 = *(const int4*)&src[base];
            int4 s1 = *(const int4*)&src[base + 4];
            int d[8] = {d0.x, d0.y, d0.z, d0.w, d1.x, d1.y, d1.z, d1.w};
            int s[8] = {s0.x, s0.y, s0.z, s0.w, s1.x, s1.y, s1.z, s1.w};
#pragma unroll
            for (int j = 0; j < 8; ++j) {
                int pos = atomicAdd(&cur[d[j] >> 9], 1);
                binned[pos] = ((unsigned int)s[j] << 9) | (unsigned int)(d[j] & 511);
            }
        } else {
            for (int e = base; e < end; ++e) {
                int dd = dst[e], ss = src[e];
                int pos = atomicAdd(&cur[dd >> 9], 1);
                binned[pos] = ((unsigned int)ss << 9) | (unsigned int)(dd & 511);
            }
        }
    }
}

// gemm1 STANDALONE (round-10 un-fuse): H[N,64](bf16) = X[N,128](fp32) @ W1.
// LDS-staged X with fp32->bf16 in staging; MFMA 16x16x32; A=Wt1.
__global__ __launch_bounds__(256) void gemm1_kernel(const float* __restrict__ X,
                                                    const unsigned short* __restrict__ Wt,
                                                    unsigned short* __restrict__ H, int N) {
    constexpr int FIN = 128;
    constexpr int KS = FIN / 32;
    constexpr int LDP = FIN + 8;
    __shared__ unsigned short sX[64 * LDP];
    int t = threadIdx.x;
    int rowBase = blockIdx.x * 64;

    for (int i = t * 4; i < 64 * FIN; i += 1024) {
        int r = i / FIN, c = i - r * FIN;
        int gr = min(rowBase + r, N - 1);
        float4 vv = *(const float4*)(X + (size_t)gr * FIN + c);
        unsigned e0 = __float_as_uint(vv.x) + 0x8000u, e1 = __float_as_uint(vv.y) + 0x8000u;
        unsigned e2 = __float_as_uint(vv.z) + 0x8000u, e3 = __float_as_uint(vv.w) + 0x8000u;
        uint2 pk;
        pk.x = __builtin_amdgcn_perm(e1, e0, 0x07060302);
        pk.y = __builtin_amdgcn_perm(e3, e2, 0x07060302);
        *(uint2*)&sX[r * LDP + c] = pk;
    }
    __syncthreads();

    int wave = t >> 6;
    int lane = t & 63;
    int r = lane & 15, g = lane >> 4;
    int node = rowBase + wave * 16 + r;

    bf16x8 afr[4][KS];
#pragma unroll
    for (int m = 0; m < 4; ++m)
#pragma unroll
        for (int s = 0; s < KS; ++s)
            afr[m][s] = *(const bf16x8*)&Wt[(m * 16 + r) * FIN + s * 32 + g * 8];

    f32x4 acc[4];
#pragma unroll
    for (int m = 0; m < 4; ++m) acc[m] = (f32x4){0.f, 0.f, 0.f, 0.f};

#pragma unroll
    for (int s = 0; s < KS; ++s) {
        bf16x8 bfr = *(const bf16x8*)&sX[(wave * 16 + r) * LDP + s * 32 + g * 8];
#pragma unroll
        for (int m = 0; m < 4; ++m)
            acc[m] = __builtin_amdgcn_mfma_f32_16x16x32_bf16(afr[m][s], bfr, acc[m], 0, 0, 0);
    }

    if (node < N) {
#pragma unroll
        for (int m = 0; m < 4; ++m) {
            ushort4 o;
            o.x = f2bf(acc[m][0]); o.y = f2bf(acc[m][1]);
            o.z = f2bf(acc[m][2]); o.w = f2bf(acc[m][3]);
            *(ushort4*)&H[(size_t)node * 64 + m * 16 + g * 4] = o;
        }
    }
}

// Per-node degree (LDS histogram) -> dinv + overflow allocation. Overflow region
// for node with deg1 = deg+1 > 24: gsl = align8(deg1-24) slots, allocated at
// per-partition fixed base align8(pbase[p]) + 4096p + localScan. ovfw[node] =
// (slotBase/8)<<7 | (gsl/8), or 0 if no overflow. NO cross-partition scan.
__global__ __launch_bounds__(512) void lsortA_kernel(const unsigned int* __restrict__ binned,
                                                     const int* __restrict__ pbase,
                                                     float* __restrict__ dinv,
                                                     int* __restrict__ ovfw, int N) {
    __shared__ int ldeg[512];
    __shared__ int s[512];
    int t = threadIdx.x, p = blockIdx.x;
    int lo = p << 9;
    ldeg[t] = 0;
    __syncthreads();
    int eBeg = pbase[p], eEnd = pbase[p + 1];
    for (int j = eBeg + t; j < eEnd; j += 512)
        atomicAdd(&ldeg[binned[j] & 511u], 1);
    __syncthreads();
    int real = ldeg[t];
    int deg1 = real + 1;
    int ovfUsed = (lo + t < N) ? max(deg1 - 24, 0) : 0;
    int gsl = ((ovfUsed + 7) >> 3) << 3;       // padded ovf slots (multiple of 8)
    s[t] = gsl;
    __syncthreads();
    for (int off = 1; off < 512; off <<= 1) {
        int u = (t >= off) ? s[t - off] : 0;
        __syncthreads();
        s[t] += u;
        __syncthreads();
    }
    if (lo + t < N) {
        dinv[lo + t] = rsqrtf((float)deg1);
        int obase = ((eBeg + 7) & ~7) + (p << 12);       // align8(pbase[p]) + 4096p
        int base = obase + (s[t] - gsl);                 // exclusive local scan
        ovfw[lo + t] = gsl ? (((base >> 3) << 7) | (gsl >> 3)) : 0;
    }
}

// Scatter: entry i (arrival order; self appended last) -> i<24: csrw[node*24+i],
// else ovf[base + i-24]. Then pads {0,0} in main tail and ovf tail.
__global__ __launch_bounds__(256) void lsortB_kernel(const unsigned int* __restrict__ binned,
                                                     const int* __restrict__ pbase,
                                                     const int* __restrict__ ovfw,
                                                     const float* __restrict__ dinv,
                                                     float2* __restrict__ csrw,
                                                     float2* __restrict__ ovf, int N) {
    __shared__ int cur[512];
    __shared__ float sdi[512];
    __shared__ int sov[512];
    int t = threadIdx.x, p = blockIdx.x;
    int lo = p << 9, span = min(N - lo, 512);
    for (int i = t; i < span; i += 256) {
        cur[i] = 0;
        sdi[i] = dinv[lo + i];
        sov[i] = ovfw[lo + i];
    }
    __syncthreads();
    int eBeg = pbase[p], eEnd = pbase[p + 1];
    for (int j = eBeg + t; j < eEnd; j += 256) {
        unsigned int vv = binned[j];
        int sr = (int)(vv >> 9);
        int dl = (int)(vv & 511u);
        int i = atomicAdd(&cur[dl], 1);
        float2 ent = make_float2(__int_as_float(sr << 7), dinv[sr] * sdi[dl]);
        if (i < 24) csrw[(size_t)(lo + dl) * 24 + i] = ent;
        else        ovf[(size_t)((sov[dl] >> 7) << 3) + i - 24] = ent;
    }
    __syncthreads();
    for (int i = t; i < span; i += 256) {
        int real = cur[i];
        int node = lo + i;
        float d = sdi[i];
        float2 self = make_float2(__int_as_float(node << 7), d * d);
        int deg1 = real + 1;
        int ob = (sov[i] >> 7) << 3;
        if (real < 24) csrw[(size_t)node * 24 + real] = self;
        else           ovf[(size_t)ob + real - 24] = self;
        for (int k = deg1; k < 24; ++k)
            csrw[(size_t)node * 24 + k] = make_float2(0.f, 0.f);     // main pads
        int gsl = (sov[i] & 127) << 3;
        for (int k = max(deg1 - 24, 0); k < gsl; ++k)
            ovf[(size_t)ob + k] = make_float2(0.f, 0.f);             // ovf pads
    }
}

// MFMA GEMM v3 (layers 2/3, bf16 input): H[N,64](bf16) = X[N,64] @ W[64,64].
// X tile staged through LDS (coalesced), fragments via ds_read_b128.
template <int FIN>
__global__ __launch_bounds__(256) void gemm_mfma_kernel(const unsigned short* __restrict__ Xv,
                                                        const unsigned short* __restrict__ Wt,
                                                        unsigned short* __restrict__ H,
                                                        int N) {
    constexpr int KS = FIN / 32;
    constexpr int LDP = FIN + 8;
    __shared__ unsigned short sX[64 * LDP];
    int tid = threadIdx.x;
    int rowBase = blockIdx.x * 64;

    for (int i = tid * 8; i < 64 * FIN; i += 2048) {
        int r = i / FIN, c = i - r * FIN;
        int gr = min(rowBase + r, N - 1);
        uint4 vv = *(const uint4*)(Xv + (size_t)gr * FIN + c);
        *(uint4*)&sX[r * LDP + c] = vv;
    }
    __syncthreads();

    int wave = tid >> 6;
    int lane = tid & 63;
    int r = lane & 15, g = lane >> 4;
    int node = rowBase + wave * 16 + r;

    bf16x8 afr[4][KS];
#pragma unroll
    for (int m = 0; m < 4; ++m)
#pragma unroll
        for (int s = 0; s < KS; ++s)
            afr[m][s] = *(const bf16x8*)&Wt[(m * 16 + r) * FIN + s * 32 + g * 8];

    f32x4 acc[4];
#pragma unroll
    for (int m = 0; m < 4; ++m) acc[m] = (f32x4){0.f, 0.f, 0.f, 0.f};

#pragma unroll
    for (int s = 0; s < KS; ++s) {
        bf16x8 bfr = *(const bf16x8*)&sX[(wave * 16 + r) * LDP + s * 32 + g * 8];
#pragma unroll
        for (int m = 0; m < 4; ++m)
            acc[m] = __builtin_amdgcn_mfma_f32_16x16x32_bf16(afr[m][s], bfr, acc[m], 0, 0, 0);
    }

    if (node < N) {
#pragma unroll
        for (int m = 0; m < 4; ++m) {
            ushort4 o;
            o.x = f2bf(acc[m][0]); o.y = f2bf(acc[m][1]);
            o.z = f2bf(acc[m][2]); o.w = f2bf(acc[m][3]);
            *(ushort4*)&H[(size_t)node * 64 + m * 16 + g * 4] = o;
        }
    }
}

// Gather step: NQ x 8 edges, unguarded (slots 8-aligned, pads weight 0).
template <int NQ>
__device__ __forceinline__ void gstep(const float2* __restrict__ csrw,
                                      const char* __restrict__ hb,
                                      int e, int g, int fo, f32x2 acc[4]) {
    float2 c[NQ];
#pragma unroll
    for (int q = 0; q < NQ; ++q) c[q] = csrw[e + 8 * q + g];
    uint4 u[NQ];
#pragma unroll
    for (int q = 0; q < NQ; ++q)
        u[q] = *(const uint4*)(hb + __float_as_int(c[q].x) + fo);
#pragma unroll
    for (int q = 0; q < NQ; ++q) {
        f32x2 w2;
        w2.x = c[q].y; w2.y = c[q].y;
        acc[0] = __builtin_elementwise_fma(w2, (f32x2){bflo(u[q].x), bfhi(u[q].x)}, acc[0]);
        acc[1] = __builtin_elementwise_fma(w2, (f32x2){bflo(u[q].y), bfhi(u[q].y)}, acc[1]);
        acc[2] = __builtin_elementwise_fma(w2, (f32x2){bflo(u[q].z), bfhi(u[q].z)}, acc[2]);
        acc[3] = __builtin_elementwise_fma(w2, (f32x2){bflo(u[q].w), bfhi(u[q].w)}, acc[3]);
    }
}

// Gather v9: one wave per dst node. lane j: edge-slot g=j>>3, feat f=j&7.
// Fixed-stride CSR: 24 slots at csrw[node*24]; overflow via packed ovfw.
__global__ __launch_bounds__(256) void gather_kernel(const float2* __restrict__ csrw,
                                                     const float2* __restrict__ ovf,
                                                     const int* __restrict__ ovfw,
                                                     const unsigned short* __restrict__ h,
                                                     const float* __restrict__ b,
                                                     unsigned short* __restrict__ aggb, int N) {
    int node = (blockIdx.x * 256 + threadIdx.x) >> 6;
    int lane = threadIdx.x & 63;
    if (node >= N) return;
    int g = lane >> 3;
    int f = lane & 7;
    int fo = f * 16;

    f32x2 acc[4];
#pragma unroll
    for (int k = 0; k < 4; ++k) acc[k] = (f32x2){0.f, 0.f};

    const char* hb = (const char*)h;
    gstep<3>(csrw, hb, node * 24, g, fo, acc);

    int ow = ovfw[node];
    if (ow) {
        int onb = ow & 127;
        int oe = (ow >> 7) << 3;
        while (onb >= 4) { gstep<4>(ovf, hb, oe, g, fo, acc); oe += 32; onb -= 4; }
        if (onb == 3)      gstep<3>(ovf, hb, oe, g, fo, acc);
        else if (onb == 2) gstep<2>(ovf, hb, oe, g, fo, acc);
        else if (onb == 1) gstep<1>(ovf, hb, oe, g, fo, acc);
    }

    float a[8];
#pragma unroll
    for (int k = 0; k < 4; ++k) { a[2 * k] = acc[k].x; a[2 * k + 1] = acc[k].y; }
#pragma unroll
    for (int k = 0; k < 8; ++k) {
        float v = a[k];
        v += __shfl_xor(v, 8);
        v += __shfl_xor(v, 16);
        v += __shfl_xor(v, 32);
        a[k] = v;
    }
    if (g == 0) {
        float4 bv0 = *(const float4*)&b[f * 8];
        float4 bv1 = *(const float4*)&b[f * 8 + 4];
        float a0 = fmaxf(a[0] + bv0.x, 0.f), a1 = fmaxf(a[1] + bv0.y, 0.f);
        float a2 = fmaxf(a[2] + bv0.z, 0.f), a3 = fmaxf(a[3] + bv0.w, 0.f);
        float a4 = fmaxf(a[4] + bv1.x, 0.f), a5 = fmaxf(a[5] + bv1.y, 0.f);
        float a6 = fmaxf(a[6] + bv1.z, 0.f), a7 = fmaxf(a[7] + bv1.w, 0.f);
        uint4 o;
        o.x = ((unsigned)f2bf(a1) << 16) | f2bf(a0);
        o.y = ((unsigned)f2bf(a3) << 16) | f2bf(a2);
        o.z = ((unsigned)f2bf(a5) << 16) | f2bf(a4);
        o.w = ((unsigned)f2bf(a7) << 16) | f2bf(a6);
        *(uint4*)&aggb[((size_t)node << 6) + f * 8] = o;
    }
}

// Pool v2: one wave per 32 contiguous nodes (lane = col). batch preloaded once
// (coalesced) + __shfl per node; all 32 row loads issued upfront.
__global__ __launch_bounds__(256) void pool_kernel(const unsigned short* __restrict__ hb,
                                                   const int* __restrict__ batch,
                                                   float* __restrict__ sums,
                                                   float* __restrict__ cnts, int N) {
    int lane = threadIdx.x & 63;
    int wid = (blockIdx.x * 256 + threadIdx.x) >> 6;
    int base = wid * 32;
    if (base >= N) return;
    int nn = min(N - base, 32);
    int bl = batch[base + min(lane & 31, nn - 1)];

    float v[32];
#pragma unroll
    for (int j = 0; j < 32; ++j) {
        int node = base + min(j, nn - 1);
        v[j] = bf2f(hb[(size_t)node * 64 + lane]);
    }

    int curg = __shfl(bl, 0);
    float acc = 0.f, cnt = 0.f;
#pragma unroll
    for (int j = 0; j < 32; ++j) {
        if (j < nn) {
            int g = __shfl(bl, j);
            if (g != curg) {
                atomicAdd(&sums[curg * 64 + lane], acc);
                if (lane == 0) atomicAdd(&cnts[curg], cnt);
                acc = 0.f; cnt = 0.f; curg = g;
            }
            acc += v[j]; cnt += 1.f;
        }
    }
    atomicAdd(&sums[curg * 64 + lane], acc);
    if (lane == 0) atomicAdd(&cnts[curg], cnt);
}

// One thread per graph: pooled = sums/cnt, logits = pooled @ Wl + bl, softmax.
__global__ void final_kernel(const float* __restrict__ sums, const float* __restrict__ cnts,
                             const float* __restrict__ Wl, const float* __restrict__ bl,
                             float* __restrict__ out, int G) {
    int g = blockIdx.x * blockDim.x + threadIdx.x;
    if (g >= G) return;
    float inv = 1.0f / fmaxf(cnts[g], 1.0f);
    float logits[10];
#pragma unroll
    for (int k = 0; k < 10; ++k) logits[k] = bl[k];
    for (int c = 0; c < 64; ++c) {
        float p = sums[g * 64 + c] * inv;
#pragma unroll
        for (int k = 0; k < 10; ++k) logits[k] = fmaf(p, Wl[c * 10 + k], logits[k]);
    }
    float m = logits[0];
#pragma unroll
    for (int k = 1; k < 10; ++k) m = fmaxf(m, logits[k]);
    float se = 0.f;
#pragma unroll
    for (int k = 0; k < 10; ++k) { logits[k] = expf(logits[k] - m); se += logits[k]; }
    float is = 1.0f / se;
#pragma unroll
    for (int k = 0; k < 10; ++k) out[g * 10 + k] = logits[k] * is;
}

extern "C" void kernel_launch(void* const* d_in, const int* in_sizes, int n_in,
                              void* d_out, int out_size, void* d_ws, size_t ws_size,
                              hipStream_t stream) {
    const float* x    = (const float*)d_in[0];
    const int* edges  = (const int*)d_in[1];
    const int* batch  = (const int*)d_in[2];
    const float* W1   = (const float*)d_in[3];
    const float* b1   = (const float*)d_in[4];
    const float* W2   = (const float*)d_in[5];
    const float* b2   = (const float*)d_in[6];
    const float* W3   = (const float*)d_in[7];
    const float* b3   = (const float*)d_in[8];
    const float* Wl   = (const float*)d_in[9];
    const float* bl   = (const float*)d_in[10];

    const int N = in_sizes[0] / 128;   // 100000
    const int E = in_sizes[1] / 2;     // 1600000
    const int G = out_size / 10;       // 64
    const int* src = edges;
    const int* dst = edges + E;

    // workspace layout (floats).
    float* ws     = (float*)d_ws;
    unsigned short* h = (unsigned short*)ws;              // N*64 bf16 = N*32 floats
    unsigned short* aggb = (unsigned short*)(ws + (size_t)N * 32);  // N*64 bf16
    unsigned int* binned = (unsigned int*)(ws + (size_t)N * 32);    // E uint, ALIASES aggb
                                                          // (dead until gather1)
    size_t o = (size_t)N * 64;
    float2* csrw  = (float2*)(ws + o);  o += (size_t)48 * N;          // 24N float2
    float2* ovf   = (float2*)(ws + o);  o += (size_t)2 * (E + 4096 * 256 + 8);
    float* dinv   = ws + o;            o += N;
    int*   ovfw   = (int*)(ws + o);    o += N;
    int*   counts = (int*)(ws + o);    o += 256 * 256;
    int*   offs   = (int*)(ws + o);    o += 256 * 256;
    int*   pbase  = (int*)(ws + o);    o += 257;
    float* sums   = ws + o;            o += (size_t)G * 64;
    float* cnts   = ws + o;            o += G;
    unsigned short* Wt1 = (unsigned short*)(ws + o);      // 64*128 + 2*64*64 shorts
    unsigned short* Wt2 = Wt1 + 64 * 128;
    unsigned short* Wt3 = Wt2 + 64 * 64;

    const int gemmGrid = (N + 63) / 64;
    const int gatherGrid = (N + 3) / 4;
    const int poolGrid = ((N + 31) / 32 + 3) / 4;
    const int P = (N + 511) >> 9;                 // 196 partitions of 512 nodes
    const int C = (((E + 255) / 256) + 7) & ~7;   // edges per chunk, multiple of 8

    // sort -> fixed-stride CSR (24 slots/node) + overflow region
    hist_kernel<<<260, 256, 0, stream>>>(dst, counts, E, P, C,
                                         W1, W2, W3, Wt1, Wt2, Wt3, sums, G);
    pscan_kernel<<<1, 256, 0, stream>>>(counts, pbase, P);
    offs_kernel<<<P, 256, 0, stream>>>(counts, pbase, offs);
    // round-10: UN-FUSED for direct per-kernel counters
    bin_kernel<<<256, 256, 0, stream>>>(src, dst, offs, binned, E, P, C);
    gemm1_kernel<<<gemmGrid, 256, 0, stream>>>(x, Wt1, h, N);
    lsortA_kernel<<<P, 512, 0, stream>>>(binned, pbase, dinv, ovfw, N);
    lsortB_kernel<<<P, 256, 0, stream>>>(binned, pbase, ovfw, dinv, csrw, ovf, N);

    // layer 1 gather
    gather_kernel<<<gatherGrid, 256, 0, stream>>>(csrw, ovf, ovfw, h, b1, aggb, N);

    // layer 2
    gemm_mfma_kernel<64><<<gemmGrid, 256, 0, stream>>>(aggb, Wt2, h, N);
    gather_kernel<<<gatherGrid, 256, 0, stream>>>(csrw, ovf, ovfw, h, b2, aggb, N);

    // layer 3
    gemm_mfma_kernel<64><<<gemmGrid, 256, 0, stream>>>(aggb, Wt3, h, N);
    gather_kernel<<<gatherGrid, 256, 0, stream>>>(csrw, ovf, ovfw, h, b3, aggb, N);

    // mean-pool per graph + head + softmax (sums/cnts zeroed in hist's extra block)
    pool_kernel<<<poolGrid, 256, 0, stream>>>(aggb, batch, sums, cnts, N);
    final_kernel<<<1, 64, 0, stream>>>(sums, cnts, Wl, bl, (float*)d_out, G);
}

// Round 11
// 336.952 us; speedup vs baseline: 1.0316x; 1.0204x over previous
//
#include <hip/hip_runtime.h>
#include <math.h>

// GCN via CSR gather. CSR(dst) built with a two-level binned counting sort;
// 3x (MFMA GEMM -> gather-agg[+relu,bf16]) -> mean-pool -> head -> softmax.
//
// NOTE: ~164us/iter = 4x __amd_rocclr_fillBufferAligned (harness workspace
// re-poison, 256MiB at 82% HBM peak, roofline) -- fixed tax, not addressable.
//
// Round 11 (this round): SLIM CSR 8B->4B + lsort fusion. csrw stores only
// src<<7 (int); gather computes w = dinv[src]*dinv[dst] (dinv = 400KB,
// L2-resident; same addr across a slot-group's 8 lanes -> broadcast). Pads
// point at dummy row N with dinv[N]=0. Gains: (1) csrw streaming per gather
// halves (24.4->12.2MB) x3; (2) scatter writes halve; (3) lsortB's 1.6M random
// dinv[src] reads vanish -> the cross-partition dinv dependency that forced
// the lsortA/lsortB split is gone -> ONE fused lsort_kernel (histogram ->
// ovf-alloc scan -> scatter -> self+pads), -1 dispatch. Weight math is
// bit-identical fp32, relocated -> absmax unchanged.
//
// Round 10: un-fused bin/gemm1 isolation -> both <40us standalone, fusion
// neutral; kept un-fused. Round 9: bin loads batched 8 edges/thread (int4
// pairs). Round 8: precomputed offs (self-computed was 54us regression).
// Gather v9 (round 6): FIXED-STRIDE CSR, 24 slots/node (deg<=23 = 96.3% of
// Poisson(16), self-loop folded in), overflow via packed ovfw[node]. Gather
// is at the random-row L3/HBM roofline (~36us/layer for 1.7Mx128B touches).
// Gather v8: merged remainder gstep<nb>, f32x2 pk_fma. Pool v2: wave/32
// nodes, batch __shfl, 32 row loads upfront. GEMM: LDS-staged X, MFMA
// 16x16x32, A=Wt bf16 (prepped in hist's extra blocks).
// N=100000 nodes, E=1.6M edges, nhid=64, Poisson(16) degrees.

typedef __attribute__((ext_vector_type(8))) short bf16x8;
typedef __attribute__((ext_vector_type(4))) float f32x4;
typedef __attribute__((ext_vector_type(2))) float f32x2;

__device__ __forceinline__ unsigned short f2bf(float f) {
    unsigned int u = __float_as_uint(f);
    u += 0x7fffu + ((u >> 16) & 1u);   // round-to-nearest-even
    return (unsigned short)(u >> 16);
}
__device__ __forceinline__ float bf2f(unsigned short u) {
    return __uint_as_float((unsigned int)u << 16);
}
__device__ __forceinline__ float bflo(unsigned int u) {
    return __uint_as_float(u << 16);
}
__device__ __forceinline__ float bfhi(unsigned int u) {
    return __uint_as_float(u & 0xffff0000u);
}

// ---- binned counting sort: partition = dst>>9 (512 nodes), P<=256, 256 chunks ----
// hist fused: blocks 256..258 = W->Wt bf16 transpose; block 259 = zero sums/cnts.

__global__ __launch_bounds__(256) void hist_kernel(const int* __restrict__ dst,
                                                   int* __restrict__ counts,
                                                   int E, int P, int C,
                                                   const float* __restrict__ W1,
                                                   const float* __restrict__ W2,
                                                   const float* __restrict__ W3,
                                                   unsigned short* __restrict__ Wt1,
                                                   unsigned short* __restrict__ Wt2,
                                                   unsigned short* __restrict__ Wt3,
                                                   float* __restrict__ sums, int G) {
    int t = threadIdx.x, b = blockIdx.x;
    if (b >= 256) {
        int xb = b - 256;
        if (xb < 3) {           // prepw
            const float* W = (xb == 0) ? W1 : ((xb == 1) ? W2 : W3);
            unsigned short* Wt = (xb == 0) ? Wt1 : ((xb == 1) ? Wt2 : Wt3);
            int K = (xb == 0) ? 128 : 64;
            int o = t & 63;
            for (int k = t >> 6; k < K; k += 4)
                Wt[o * K + k] = f2bf(W[k * 64 + o]);
        } else {                // zero sums+cnts (G*65 floats)
            for (int i = t; i < G * 65; i += 256) sums[i] = 0.f;
        }
        return;
    }
    __shared__ int hist[256];
    if (t < P) hist[t] = 0;
    __syncthreads();
    int beg = b * C, end = min(E, beg + C);
    for (int e = beg + t; e < end; e += 256)
        atomicAdd(&hist[dst[e] >> 9], 1);
    __syncthreads();
    if (t < P) counts[t * 256 + b] = hist[t];
}

__global__ __launch_bounds__(256) void pscan_kernel(const int* __restrict__ counts,
                                                    int* __restrict__ pbase,
                                                    int P) {
    __shared__ int s[256];
    int t = threadIdx.x;
    int v = 0;
    if (t < P)
        for (int b = 0; b < 256; ++b) v += counts[t * 256 + b];
    s[t] = v;
    __syncthreads();
    for (int off = 1; off < 256; off <<= 1) {
        int u = (t >= off) ? s[t - off] : 0;
        __syncthreads();
        s[t] += u;
        __syncthreads();
    }
    if (t < P) pbase[t] = s[t] - v;
    if (t == 255) pbase[P] = s[255];
}

// Per-partition chunk-offset table: offs[p*256+t] = pbase[p] + prefix of
// counts[p*256+*] over chunks < t. Coalesced LDS scan, P blocks.
__global__ __launch_bounds__(256) void offs_kernel(const int* __restrict__ counts,
                                                   const int* __restrict__ pbase,
                                                   int* __restrict__ offs) {
    __shared__ int s[256];
    int t = threadIdx.x, p = blockIdx.x;
    int v = counts[p * 256 + t];
    s[t] = v;
    __syncthreads();
    for (int off = 1; off < 256; off <<= 1) {
        int u = (t >= off) ? s[t - off] : 0;
        __syncthreads();
        s[t] += u;
        __syncthreads();
    }
    offs[p * 256 + t] = pbase[p] + s[t] - v;
}

// bin scatter: 8 contiguous edges per thread per pass; int4-pair loads issued
// up front (16B-aligned, C%8==0) so load latency is paid once per 8 edges.
__global__ __launch_bounds__(256) void bin_kernel(const int* __restrict__ src,
                                                  const int* __restrict__ dst,
                                                  const int* __restrict__ offs,
                                                  unsigned int* __restrict__ binned,
                                                  int E, int P, int C) {
    __shared__ int cur[256];
    int t = threadIdx.x, b = blockIdx.x;
    if (t < P) cur[t] = offs[t * 256 + b];
    __syncthreads();
    int beg = b * C, end = min(E, beg + C);
    for (int base = beg + t * 8; base < end; base += 2048) {
        if (base + 8 <= end) {
            int4 d0 = *(const int4*)&dst[base];
            int4 d1 = *(const int4*)&dst[base + 4];
            int4 s0 = *(const int4*)&src[base];
            int4 s1 = *(const int4*)&src[base + 4];
            int d[8] = {d0.x, d0.y, d0.z, d0.w, d1.x, d1.y, d1.z, d1.w};
            int s[8] = {s0.x, s0.y, s0.z, s0.w, s1.x, s1.y, s1.z, s1.w};
#pragma unroll
            for (int j = 0; j < 8; ++j) {
                int pos = atomicAdd(&cur[d[j] >> 9], 1);
                binned[pos] = ((unsigned int)s[j] << 9) | (unsigned int)(d[j] & 511);
            }
        } else {
            for (int e = base; e < end; ++e) {
                int dd = dst[e], ss = src[e];
                int pos = atomicAdd(&cur[dd >> 9], 1);
                binned[pos] = ((unsigned int)ss << 9) | (unsigned int)(dd & 511);
            }
        }
    }
}

// gemm1: H[N,64](bf16) = X[N,128](fp32) @ W1. LDS-staged X (fp32->bf16 in
// staging, +0x8000 half-up + v_perm pack); MFMA 16x16x32; A=Wt1.
__global__ __launch_bounds__(256) void gemm1_kernel(const float* __restrict__ X,
                                                    const unsigned short* __restrict__ Wt,
                                                    unsigned short* __restrict__ H, int N) {
    constexpr int FIN = 128;
    constexpr int KS = FIN / 32;
    constexpr int LDP = FIN + 8;
    __shared__ unsigned short sX[64 * LDP];
    int t = threadIdx.x;
    int rowBase = blockIdx.x * 64;

    for (int i = t * 4; i < 64 * FIN; i += 1024) {
        int r = i / FIN, c = i - r * FIN;
        int gr = min(rowBase + r, N - 1);
        float4 vv = *(const float4*)(X + (size_t)gr * FIN + c);
        unsigned e0 = __float_as_uint(vv.x) + 0x8000u, e1 = __float_as_uint(vv.y) + 0x8000u;
        unsigned e2 = __float_as_uint(vv.z) + 0x8000u, e3 = __float_as_uint(vv.w) + 0x8000u;
        uint2 pk;
        pk.x = __builtin_amdgcn_perm(e1, e0, 0x07060302);
        pk.y = __builtin_amdgcn_perm(e3, e2, 0x07060302);
        *(uint2*)&sX[r * LDP + c] = pk;
    }
    __syncthreads();

    int wave = t >> 6;
    int lane = t & 63;
    int r = lane & 15, g = lane >> 4;
    int node = rowBase + wave * 16 + r;

    bf16x8 afr[4][KS];
#pragma unroll
    for (int m = 0; m < 4; ++m)
#pragma unroll
        for (int s = 0; s < KS; ++s)
            afr[m][s] = *(const bf16x8*)&Wt[(m * 16 + r) * FIN + s * 32 + g * 8];

    f32x4 acc[4];
#pragma unroll
    for (int m = 0; m < 4; ++m) acc[m] = (f32x4){0.f, 0.f, 0.f, 0.f};

#pragma unroll
    for (int s = 0; s < KS; ++s) {
        bf16x8 bfr = *(const bf16x8*)&sX[(wave * 16 + r) * LDP + s * 32 + g * 8];
#pragma unroll
        for (int m = 0; m < 4; ++m)
            acc[m] = __builtin_amdgcn_mfma_f32_16x16x32_bf16(afr[m][s], bfr, acc[m], 0, 0, 0);
    }

    if (node < N) {
#pragma unroll
        for (int m = 0; m < 4; ++m) {
            ushort4 o;
            o.x = f2bf(acc[m][0]); o.y = f2bf(acc[m][1]);
            o.z = f2bf(acc[m][2]); o.w = f2bf(acc[m][3]);
            *(ushort4*)&H[(size_t)node * 64 + m * 16 + g * 4] = o;
        }
    }
}

// Fused lsort (round 11; replaces lsortA+lsortB): per partition (512 nodes):
// (1) LDS degree histogram over binned span; (2) dinv + ovf allocation
// (local scan, per-partition fixed base align8(pbase[p]) + 4096p); (3) scatter
// src<<7 ints to csrw[node*24 + i] / ovf[base + i-24]; (4) self entry + pads
// = N<<7 (dummy row, dinv[N]=0 -> weight 0 in gather). No dinv[src] reads
// here -- weights are computed in gather from L2-resident dinv.
__global__ __launch_bounds__(512) void lsort_kernel(const unsigned int* __restrict__ binned,
                                                    const int* __restrict__ pbase,
                                                    float* __restrict__ dinv,
                                                    int* __restrict__ ovfw,
                                                    int* __restrict__ csrw,
                                                    int* __restrict__ ovf, int N) {
    __shared__ int ldeg[512];
    __shared__ int s[512];
    __shared__ int sob[512];
    int t = threadIdx.x, p = blockIdx.x;
    int lo = p << 9;
    ldeg[t] = 0;
    __syncthreads();
    int eBeg = pbase[p], eEnd = pbase[p + 1];
    for (int j = eBeg + t; j < eEnd; j += 512)
        atomicAdd(&ldeg[binned[j] & 511u], 1);
    __syncthreads();
    int real = ldeg[t];
    int deg1 = real + 1;
    int ovfUsed = (lo + t < N) ? max(deg1 - 24, 0) : 0;
    int gsl = ((ovfUsed + 7) >> 3) << 3;       // padded ovf slots (multiple of 8)
    s[t] = gsl;
    __syncthreads();
    for (int off = 1; off < 512; off <<= 1) {
        int u = (t >= off) ? s[t - off] : 0;
        __syncthreads();
        s[t] += u;
        __syncthreads();
    }
    int obase = ((eBeg + 7) & ~7) + (p << 12);           // align8(pbase[p]) + 4096p
    int myOvf = obase + (s[t] - gsl);                    // exclusive local scan
    int ow = gsl ? (((myOvf >> 3) << 7) | (gsl >> 3)) : 0;
    if (lo + t < N) {
        dinv[lo + t] = rsqrtf((float)deg1);
        ovfw[lo + t] = ow;
    }
    if (p == 0 && t == 0) dinv[N] = 0.f;                 // dummy row: pad weight 0
    __syncthreads();
    ldeg[t] = 0;                                         // reuse as scatter cursor
    sob[t] = myOvf;
    __syncthreads();
    for (int j = eBeg + t; j < eEnd; j += 512) {
        unsigned int vv = binned[j];
        int sr = (int)(vv >> 9);
        int dl = (int)(vv & 511u);
        int i = atomicAdd(&ldeg[dl], 1);
        int ent = sr << 7;
        if (i < 24) csrw[(size_t)(lo + dl) * 24 + i] = ent;
        else        ovf[sob[dl] + i - 24] = ent;
    }
    __syncthreads();
    if (lo + t < N) {
        int node = lo + t;
        int dcur = ldeg[t];                              // == real
        int self = node << 7;
        if (dcur < 24) csrw[(size_t)node * 24 + dcur] = self;
        else           ovf[sob[t] + dcur - 24] = self;
        int pad = N << 7;
        for (int k = dcur + 1; k < 24; ++k)
            csrw[(size_t)node * 24 + k] = pad;           // main pads
        int og = (ow & 127) << 3;
        for (int k = max(dcur + 1 - 24, 0); k < og; ++k)
            ovf[sob[t] + k] = pad;                       // ovf pads
    }
}

// MFMA GEMM (layers 2/3, bf16 input): H[N,64](bf16) = X[N,64] @ W[64,64].
// X tile staged through LDS (coalesced), fragments via ds_read_b128.
template <int FIN>
__global__ __launch_bounds__(256) void gemm_mfma_kernel(const unsigned short* __restrict__ Xv,
                                                        const unsigned short* __restrict__ Wt,
                                                        unsigned short* __restrict__ H,
                                                        int N) {
    constexpr int KS = FIN / 32;
    constexpr int LDP = FIN + 8;
    __shared__ unsigned short sX[64 * LDP];
    int tid = threadIdx.x;
    int rowBase = blockIdx.x * 64;

    for (int i = tid * 8; i < 64 * FIN; i += 2048) {
        int r = i / FIN, c = i - r * FIN;
        int gr = min(rowBase + r, N - 1);
        uint4 vv = *(const uint4*)(Xv + (size_t)gr * FIN + c);
        *(uint4*)&sX[r * LDP + c] = vv;
    }
    __syncthreads();

    int wave = tid >> 6;
    int lane = tid & 63;
    int r = lane & 15, g = lane >> 4;
    int node = rowBase + wave * 16 + r;

    bf16x8 afr[4][KS];
#pragma unroll
    for (int m = 0; m < 4; ++m)
#pragma unroll
        for (int s = 0; s < KS; ++s)
            afr[m][s] = *(const bf16x8*)&Wt[(m * 16 + r) * FIN + s * 32 + g * 8];

    f32x4 acc[4];
#pragma unroll
    for (int m = 0; m < 4; ++m) acc[m] = (f32x4){0.f, 0.f, 0.f, 0.f};

#pragma unroll
    for (int s = 0; s < KS; ++s) {
        bf16x8 bfr = *(const bf16x8*)&sX[(wave * 16 + r) * LDP + s * 32 + g * 8];
#pragma unroll
        for (int m = 0; m < 4; ++m)
            acc[m] = __builtin_amdgcn_mfma_f32_16x16x32_bf16(afr[m][s], bfr, acc[m], 0, 0, 0);
    }

    if (node < N) {
#pragma unroll
        for (int m = 0; m < 4; ++m) {
            ushort4 o;
            o.x = f2bf(acc[m][0]); o.y = f2bf(acc[m][1]);
            o.z = f2bf(acc[m][2]); o.w = f2bf(acc[m][3]);
            *(ushort4*)&H[(size_t)node * 64 + m * 16 + g * 4] = o;
        }
    }
}

// Gather step v10: NQ x 8 edges, unguarded. csrw entries are src<<7 ints;
// weight = dinv[src]*di computed here (dinv 400KB, L2-resident; same addr
// across a slot-group's 8 lanes -> broadcast). Pads hit dummy row N, dinv=0.
template <int NQ>
__device__ __forceinline__ void gstep(const int* __restrict__ csrw,
                                      const float* __restrict__ dinv,
                                      const char* __restrict__ hb, float di,
                                      int e, int g, int fo, f32x2 acc[4]) {
    int c[NQ];
#pragma unroll
    for (int q = 0; q < NQ; ++q) c[q] = csrw[e + 8 * q + g];
    float w[NQ];
    uint4 u[NQ];
#pragma unroll
    for (int q = 0; q < NQ; ++q) w[q] = dinv[c[q] >> 7];
#pragma unroll
    for (int q = 0; q < NQ; ++q)
        u[q] = *(const uint4*)(hb + c[q] + fo);
#pragma unroll
    for (int q = 0; q < NQ; ++q) {
        float wq = w[q] * di;
        f32x2 w2;
        w2.x = wq; w2.y = wq;
        acc[0] = __builtin_elementwise_fma(w2, (f32x2){bflo(u[q].x), bfhi(u[q].x)}, acc[0]);
        acc[1] = __builtin_elementwise_fma(w2, (f32x2){bflo(u[q].y), bfhi(u[q].y)}, acc[1]);
        acc[2] = __builtin_elementwise_fma(w2, (f32x2){bflo(u[q].z), bfhi(u[q].z)}, acc[2]);
        acc[3] = __builtin_elementwise_fma(w2, (f32x2){bflo(u[q].w), bfhi(u[q].w)}, acc[3]);
    }
}

// Gather v10: one wave per dst node. lane j: edge-slot g=j>>3, feat f=j&7.
// Fixed-stride CSR: 24 int slots at csrw[node*24]; overflow via packed ovfw.
__global__ __launch_bounds__(256) void gather_kernel(const int* __restrict__ csrw,
                                                     const int* __restrict__ ovf,
                                                     const int* __restrict__ ovfw,
                                                     const float* __restrict__ dinv,
                                                     const unsigned short* __restrict__ h,
                                                     const float* __restrict__ b,
                                                     unsigned short* __restrict__ aggb, int N) {
    int node = (blockIdx.x * 256 + threadIdx.x) >> 6;
    int lane = threadIdx.x & 63;
    if (node >= N) return;
    int g = lane >> 3;
    int f = lane & 7;
    int fo = f * 16;
    float di = dinv[node];

    f32x2 acc[4];
#pragma unroll
    for (int k = 0; k < 4; ++k) acc[k] = (f32x2){0.f, 0.f};

    const char* hb = (const char*)h;
    gstep<3>(csrw, dinv, hb, di, node * 24, g, fo, acc);

    int ow = ovfw[node];
    if (ow) {
        int onb = ow & 127;
        int oe = (ow >> 7) << 3;
        while (onb >= 4) { gstep<4>(ovf, dinv, hb, di, oe, g, fo, acc); oe += 32; onb -= 4; }
        if (onb == 3)      gstep<3>(ovf, dinv, hb, di, oe, g, fo, acc);
        else if (onb == 2) gstep<2>(ovf, dinv, hb, di, oe, g, fo, acc);
        else if (onb == 1) gstep<1>(ovf, dinv, hb, di, oe, g, fo, acc);
    }

    float a[8];
#pragma unroll
    for (int k = 0; k < 4; ++k) { a[2 * k] = acc[k].x; a[2 * k + 1] = acc[k].y; }
#pragma unroll
    for (int k = 0; k < 8; ++k) {
        float v = a[k];
        v += __shfl_xor(v, 8);
        v += __shfl_xor(v, 16);
        v += __shfl_xor(v, 32);
        a[k] = v;
    }
    if (g == 0) {
        float4 bv0 = *(const float4*)&b[f * 8];
        float4 bv1 = *(const float4*)&b[f * 8 + 4];
        float a0 = fmaxf(a[0] + bv0.x, 0.f), a1 = fmaxf(a[1] + bv0.y, 0.f);
        float a2 = fmaxf(a[2] + bv0.z, 0.f), a3 = fmaxf(a[3] + bv0.w, 0.f);
        float a4 = fmaxf(a[4] + bv1.x, 0.f), a5 = fmaxf(a[5] + bv1.y, 0.f);
        float a6 = fmaxf(a[6] + bv1.z, 0.f), a7 = fmaxf(a[7] + bv1.w, 0.f);
        uint4 o;
        o.x = ((unsigned)f2bf(a1) << 16) | f2bf(a0);
        o.y = ((unsigned)f2bf(a3) << 16) | f2bf(a2);
        o.z = ((unsigned)f2bf(a5) << 16) | f2bf(a4);
        o.w = ((unsigned)f2bf(a7) << 16) | f2bf(a6);
        *(uint4*)&aggb[((size_t)node << 6) + f * 8] = o;
    }
}

// Pool v2: one wave per 32 contiguous nodes (lane = col). batch preloaded once
// (coalesced) + __shfl per node; all 32 row loads issued upfront.
__global__ __launch_bounds__(256) void pool_kernel(const unsigned short* __restrict__ hb,
                                                   const int* __restrict__ batch,
                                                   float* __restrict__ sums,
                                                   float* __restrict__ cnts, int N) {
    int lane = threadIdx.x & 63;
    int wid = (blockIdx.x * 256 + threadIdx.x) >> 6;
    int base = wid * 32;
    if (base >= N) return;
    int nn = min(N - base, 32);
    int bl = batch[base + min(lane & 31, nn - 1)];

    float v[32];
#pragma unroll
    for (int j = 0; j < 32; ++j) {
        int node = base + min(j, nn - 1);
        v[j] = bf2f(hb[(size_t)node * 64 + lane]);
    }

    int curg = __shfl(bl, 0);
    float acc = 0.f, cnt = 0.f;
#pragma unroll
    for (int j = 0; j < 32; ++j) {
        if (j < nn) {
            int g = __shfl(bl, j);
            if (g != curg) {
                atomicAdd(&sums[curg * 64 + lane], acc);
                if (lane == 0) atomicAdd(&cnts[curg], cnt);
                acc = 0.f; cnt = 0.f; curg = g;
            }
            acc += v[j]; cnt += 1.f;
        }
    }
    atomicAdd(&sums[curg * 64 + lane], acc);
    if (lane == 0) atomicAdd(&cnts[curg], cnt);
}

// One thread per graph: pooled = sums/cnt, logits = pooled @ Wl + bl, softmax.
__global__ void final_kernel(const float* __restrict__ sums, const float* __restrict__ cnts,
                             const float* __restrict__ Wl, const float* __restrict__ bl,
                             float* __restrict__ out, int G) {
    int g = blockIdx.x * blockDim.x + threadIdx.x;
    if (g >= G) return;
    float inv = 1.0f / fmaxf(cnts[g], 1.0f);
    float logits[10];
#pragma unroll
    for (int k = 0; k < 10; ++k) logits[k] = bl[k];
    for (int c = 0; c < 64; ++c) {
        float p = sums[g * 64 + c] * inv;
#pragma unroll
        for (int k = 0; k < 10; ++k) logits[k] = fmaf(p, Wl[c * 10 + k], logits[k]);
    }
    float m = logits[0];
#pragma unroll
    for (int k = 1; k < 10; ++k) m = fmaxf(m, logits[k]);
    float se = 0.f;
#pragma unroll
    for (int k = 0; k < 10; ++k) { logits[k] = expf(logits[k] - m); se += logits[k]; }
    float is = 1.0f / se;
#pragma unroll
    for (int k = 0; k < 10; ++k) out[g * 10 + k] = logits[k] * is;
}

extern "C" void kernel_launch(void* const* d_in, const int* in_sizes, int n_in,
                              void* d_out, int out_size, void* d_ws, size_t ws_size,
                              hipStream_t stream) {
    const float* x    = (const float*)d_in[0];
    const int* edges  = (const int*)d_in[1];
    const int* batch  = (const int*)d_in[2];
    const float* W1   = (const float*)d_in[3];
    const float* b1   = (const float*)d_in[4];
    const float* W2   = (const float*)d_in[5];
    const float* b2   = (const float*)d_in[6];
    const float* W3   = (const float*)d_in[7];
    const float* b3   = (const float*)d_in[8];
    const float* Wl   = (const float*)d_in[9];
    const float* bl   = (const float*)d_in[10];

    const int N = in_sizes[0] / 128;   // 100000
    const int E = in_sizes[1] / 2;     // 1600000
    const int G = out_size / 10;       // 64
    const int* src = edges;
    const int* dst = edges + E;

    // workspace layout (floats). h row N (pad dummy) reads into aggb start --
    // harmless (weight 0).
    float* ws     = (float*)d_ws;
    unsigned short* h = (unsigned short*)ws;              // N*64 bf16 = N*32 floats
    unsigned short* aggb = (unsigned short*)(ws + (size_t)N * 32);  // N*64 bf16
    unsigned int* binned = (unsigned int*)(ws + (size_t)N * 32);    // E uint, ALIASES aggb
                                                          // (dead until gather1)
    size_t o = (size_t)N * 64;
    int*   csrw   = (int*)(ws + o);    o += (size_t)24 * N;           // 24N ints (src<<7)
    int*   ovf    = (int*)(ws + o);    o += (size_t)E + 4096 * 256 + 8;
    float* dinv   = ws + o;            o += N + 1;        // +1: dinv[N]=0 dummy
    int*   ovfw   = (int*)(ws + o);    o += N;
    int*   counts = (int*)(ws + o);    o += 256 * 256;
    int*   offs   = (int*)(ws + o);    o += 256 * 256;
    int*   pbase  = (int*)(ws + o);    o += 257;
    float* sums   = ws + o;            o += (size_t)G * 64;
    float* cnts   = ws + o;            o += G;
    unsigned short* Wt1 = (unsigned short*)(ws + o);      // 64*128 + 2*64*64 shorts
    unsigned short* Wt2 = Wt1 + 64 * 128;
    unsigned short* Wt3 = Wt2 + 64 * 64;

    const int gemmGrid = (N + 63) / 64;
    const int gatherGrid = (N + 3) / 4;
    const int poolGrid = ((N + 31) / 32 + 3) / 4;
    const int P = (N + 511) >> 9;                 // 196 partitions of 512 nodes
    const int C = (((E + 255) / 256) + 7) & ~7;   // edges per chunk, multiple of 8

    // sort -> fixed-stride CSR (24 int slots/node, src<<7) + overflow region
    hist_kernel<<<260, 256, 0, stream>>>(dst, counts, E, P, C,
                                         W1, W2, W3, Wt1, Wt2, Wt3, sums, G);
    pscan_kernel<<<1, 256, 0, stream>>>(counts, pbase, P);
    offs_kernel<<<P, 256, 0, stream>>>(counts, pbase, offs);
    bin_kernel<<<256, 256, 0, stream>>>(src, dst, offs, binned, E, P, C);
    gemm1_kernel<<<gemmGrid, 256, 0, stream>>>(x, Wt1, h, N);
    lsort_kernel<<<P, 512, 0, stream>>>(binned, pbase, dinv, ovfw, csrw, ovf, N);

    // layer 1 gather
    gather_kernel<<<gatherGrid, 256, 0, stream>>>(csrw, ovf, ovfw, dinv, h, b1, aggb, N);

    // layer 2
    gemm_mfma_kernel<64><<<gemmGrid, 256, 0, stream>>>(aggb, Wt2, h, N);
    gather_kernel<<<gatherGrid, 256, 0, stream>>>(csrw, ovf, ovfw, dinv, h, b2, aggb, N);

    // layer 3
    gemm_mfma_kernel<64><<<gemmGrid, 256, 0, stream>>>(aggb, Wt3, h, N);
    gather_kernel<<<gatherGrid, 256, 0, stream>>>(csrw, ovf, ovfw, dinv, h, b3, aggb, N);

    // mean-pool per graph + head + softmax (sums/cnts zeroed in hist's extra block)
    pool_kernel<<<poolGrid, 256, 0, stream>>>(aggb, batch, sums, cnts, N);
    final_kernel<<<1, 64, 0, stream>>>(sums, cnts, Wl, bl, (float*)d_out, G);
}

// Round 12
// 333.946 us; speedup vs baseline: 1.0409x; 1.0090x over previous
//
#include <hip/hip_runtime.h>
#include <math.h>

// GCN via CSR gather. CSR(dst) built with a two-level binned counting sort;
// 3x (MFMA GEMM -> gather-agg[+relu,bf16]) -> mean-pool -> head -> softmax.
//
// NOTE: ~165us/iter = 4x __amd_rocclr_fillBufferAligned (harness workspace
// re-poison, 256MiB at 82% HBM peak, roofline) -- fixed tax, not addressable.
// Gather (3x ~33us) is at the random-row L2-miss wall (rounds 6/10 analysis).
//
// Round 12 (this round): the sort pipeline still carried three copies of the
// round-9 pathology (load->LDS-atomic serial chain, one exposed latency per
// iteration) plus a 1-block uncoalesced scan:
//  (1) counts TRANSPOSED to chunk-major counts[b*256+t]: hist write and
//      pscan read become lane-consecutive. pscan is 1 block (4 waves, no TLP)
//      so its 64-line-per-iter stride-1KB reads were pure exposed latency;
//      the cost moves to offs/bin reads which are multi-block + L2-resident.
//  (2) hist batched 8 edges/thread/pass (int4 pairs up front, then 8 atomics).
//  (3) lsort batched 4 edges/thread/pass in histogram AND scatter loops
//      (stride-512 scalar loads issued up front; guarded main + scalar tail).
//
// Round 11: slim CSR 8B->4B (csrw = src<<7; w computed in gather from
// L2-resident dinv; pads -> dummy row N, dinv[N]=0) + fused lsort. Round 10:
// un-fused bin/gemm1 (fusion neutral). Round 9: bin 8-edge batched loads.
// Round 8: precomputed offs. Gather v9/v10: FIXED-STRIDE CSR, 24 slots/node,
// overflow via packed ovfw[node]. Gather v8: merged remainder gstep<nb>,
// f32x2 pk_fma. Pool v2: wave/32 nodes, batch __shfl, rows upfront. GEMM:
// LDS-staged X, MFMA 16x16x32, A=Wt bf16 (prepped in hist's extra blocks).
// N=100000 nodes, E=1.6M edges, nhid=64, Poisson(16) degrees.

typedef __attribute__((ext_vector_type(8))) short bf16x8;
typedef __attribute__((ext_vector_type(4))) float f32x4;
typedef __attribute__((ext_vector_type(2))) float f32x2;

__device__ __forceinline__ unsigned short f2bf(float f) {
    unsigned int u = __float_as_uint(f);
    u += 0x7fffu + ((u >> 16) & 1u);   // round-to-nearest-even
    return (unsigned short)(u >> 16);
}
__device__ __forceinline__ float bf2f(unsigned short u) {
    return __uint_as_float((unsigned int)u << 16);
}
__device__ __forceinline__ float bflo(unsigned int u) {
    return __uint_as_float(u << 16);
}
__device__ __forceinline__ float bfhi(unsigned int u) {
    return __uint_as_float(u & 0xffff0000u);
}

// ---- binned counting sort: partition = dst>>9 (512 nodes), P<=256, 256 chunks ----
// counts is CHUNK-MAJOR: counts[b*256 + t] (b = chunk, t = partition).
// hist fused: blocks 256..258 = W->Wt bf16 transpose; block 259 = zero sums/cnts.

__global__ __launch_bounds__(256) void hist_kernel(const int* __restrict__ dst,
                                                   int* __restrict__ counts,
                                                   int E, int P, int C,
                                                   const float* __restrict__ W1,
                                                   const float* __restrict__ W2,
                                                   const float* __restrict__ W3,
                                                   unsigned short* __restrict__ Wt1,
                                                   unsigned short* __restrict__ Wt2,
                                                   unsigned short* __restrict__ Wt3,
                                                   float* __restrict__ sums, int G) {
    int t = threadIdx.x, b = blockIdx.x;
    if (b >= 256) {
        int xb = b - 256;
        if (xb < 3) {           // prepw
            const float* W = (xb == 0) ? W1 : ((xb == 1) ? W2 : W3);
            unsigned short* Wt = (xb == 0) ? Wt1 : ((xb == 1) ? Wt2 : Wt3);
            int K = (xb == 0) ? 128 : 64;
            int o = t & 63;
            for (int k = t >> 6; k < K; k += 4)
                Wt[o * K + k] = f2bf(W[k * 64 + o]);
        } else {                // zero sums+cnts (G*65 floats)
            for (int i = t; i < G * 65; i += 256) sums[i] = 0.f;
        }
        return;
    }
    __shared__ int hist[256];
    if (t < P) hist[t] = 0;
    __syncthreads();
    int beg = b * C, end = min(E, beg + C);
    // batched: 8 edges/thread/pass, int4-pair loads up front (beg 32B-aligned,
    // C%8==0), then 8 LDS atomics -- latency paid once per 8 edges.
    for (int base = beg + t * 8; base < end; base += 2048) {
        if (base + 8 <= end) {
            int4 d0 = *(const int4*)&dst[base];
            int4 d1 = *(const int4*)&dst[base + 4];
            int d[8] = {d0.x, d0.y, d0.z, d0.w, d1.x, d1.y, d1.z, d1.w};
#pragma unroll
            for (int j = 0; j < 8; ++j) atomicAdd(&hist[d[j] >> 9], 1);
        } else {
            for (int e = base; e < end; ++e) atomicAdd(&hist[dst[e] >> 9], 1);
        }
    }
    __syncthreads();
    if (t < P) counts[b * 256 + t] = hist[t];   // chunk-major: coalesced write
}

// 1 block: pbase[t] = exclusive scan over partitions of total counts.
// chunk-major counts -> the per-chunk reads are lane-consecutive (coalesced).
__global__ __launch_bounds__(256) void pscan_kernel(const int* __restrict__ counts,
                                                    int* __restrict__ pbase,
                                                    int P) {
    __shared__ int s[256];
    int t = threadIdx.x;
    int v = 0;
    if (t < P)
        for (int b = 0; b < 256; ++b) v += counts[b * 256 + t];
    s[t] = v;
    __syncthreads();
    for (int off = 1; off < 256; off <<= 1) {
        int u = (t >= off) ? s[t - off] : 0;
        __syncthreads();
        s[t] += u;
        __syncthreads();
    }
    if (t < P) pbase[t] = s[t] - v;
    if (t == 255) pbase[P] = s[255];
}

// Per-partition chunk-offset table: offs[p*256+t] = pbase[p] + prefix of
// chunk counts for partition p over chunks < t. Reads are strided (chunk-major
// counts) but multi-block + L2-resident -> latency hidden.
__global__ __launch_bounds__(256) void offs_kernel(const int* __restrict__ counts,
                                                   const int* __restrict__ pbase,
                                                   int* __restrict__ offs) {
    __shared__ int s[256];
    int t = threadIdx.x, p = blockIdx.x;
    int v = counts[t * 256 + p];
    s[t] = v;
    __syncthreads();
    for (int off = 1; off < 256; off <<= 1) {
        int u = (t >= off) ? s[t - off] : 0;
        __syncthreads();
        s[t] += u;
        __syncthreads();
    }
    offs[p * 256 + t] = pbase[p] + s[t] - v;
}

// bin scatter: 8 contiguous edges per thread per pass; int4-pair loads issued
// up front (16B-aligned, C%8==0) so load latency is paid once per 8 edges.
__global__ __launch_bounds__(256) void bin_kernel(const int* __restrict__ src,
                                                  const int* __restrict__ dst,
                                                  const int* __restrict__ offs,
                                                  unsigned int* __restrict__ binned,
                                                  int E, int P, int C) {
    __shared__ int cur[256];
    int t = threadIdx.x, b = blockIdx.x;
    if (t < P) cur[t] = offs[t * 256 + b];
    __syncthreads();
    int beg = b * C, end = min(E, beg + C);
    for (int base = beg + t * 8; base < end; base += 2048) {
        if (base + 8 <= end) {
            int4 d0 = *(const int4*)&dst[base];
            int4 d1 = *(const int4*)&dst[base + 4];
            int4 s0 = *(const int4*)&src[base];
            int4 s1 = *(const int4*)&src[base + 4];
            int d[8] = {d0.x, d0.y, d0.z, d0.w, d1.x, d1.y, d1.z, d1.w};
            int s[8] = {s0.x, s0.y, s0.z, s0.w, s1.x, s1.y, s1.z, s1.w};
#pragma unroll
            for (int j = 0; j < 8; ++j) {
                int pos = atomicAdd(&cur[d[j] >> 9], 1);
                binned[pos] = ((unsigned int)s[j] << 9) | (unsigned int)(d[j] & 511);
            }
        } else {
            for (int e = base; e < end; ++e) {
                int dd = dst[e], ss = src[e];
                int pos = atomicAdd(&cur[dd >> 9], 1);
                binned[pos] = ((unsigned int)ss << 9) | (unsigned int)(dd & 511);
            }
        }
    }
}

// gemm1: H[N,64](bf16) = X[N,128](fp32) @ W1. LDS-staged X (fp32->bf16 in
// staging, +0x8000 half-up + v_perm pack); MFMA 16x16x32; A=Wt1.
__global__ __launch_bounds__(256) void gemm1_kernel(const float* __restrict__ X,
                                                    const unsigned short* __restrict__ Wt,
                                                    unsigned short* __restrict__ H, int N) {
    constexpr int FIN = 128;
    constexpr int KS = FIN / 32;
    constexpr int LDP = FIN + 8;
    __shared__ unsigned short sX[64 * LDP];
    int t = threadIdx.x;
    int rowBase = blockIdx.x * 64;

    for (int i = t * 4; i < 64 * FIN; i += 1024) {
        int r = i / FIN, c = i - r * FIN;
        int gr = min(rowBase + r, N - 1);
        float4 vv = *(const float4*)(X + (size_t)gr * FIN + c);
        unsigned e0 = __float_as_uint(vv.x) + 0x8000u, e1 = __float_as_uint(vv.y) + 0x8000u;
        unsigned e2 = __float_as_uint(vv.z) + 0x8000u, e3 = __float_as_uint(vv.w) + 0x8000u;
        uint2 pk;
        pk.x = __builtin_amdgcn_perm(e1, e0, 0x07060302);
        pk.y = __builtin_amdgcn_perm(e3, e2, 0x07060302);
        *(uint2*)&sX[r * LDP + c] = pk;
    }
    __syncthreads();

    int wave = t >> 6;
    int lane = t & 63;
    int r = lane & 15, g = lane >> 4;
    int node = rowBase + wave * 16 + r;

    bf16x8 afr[4][KS];
#pragma unroll
    for (int m = 0; m < 4; ++m)
#pragma unroll
        for (int s = 0; s < KS; ++s)
            afr[m][s] = *(const bf16x8*)&Wt[(m * 16 + r) * FIN + s * 32 + g * 8];

    f32x4 acc[4];
#pragma unroll
    for (int m = 0; m < 4; ++m) acc[m] = (f32x4){0.f, 0.f, 0.f, 0.f};

#pragma unroll
    for (int s = 0; s < KS; ++s) {
        bf16x8 bfr = *(const bf16x8*)&sX[(wave * 16 + r) * LDP + s * 32 + g * 8];
#pragma unroll
        for (int m = 0; m < 4; ++m)
            acc[m] = __builtin_amdgcn_mfma_f32_16x16x32_bf16(afr[m][s], bfr, acc[m], 0, 0, 0);
    }

    if (node < N) {
#pragma unroll
        for (int m = 0; m < 4; ++m) {
            ushort4 o;
            o.x = f2bf(acc[m][0]); o.y = f2bf(acc[m][1]);
            o.z = f2bf(acc[m][2]); o.w = f2bf(acc[m][3]);
            *(ushort4*)&H[(size_t)node * 64 + m * 16 + g * 4] = o;
        }
    }
}

// Fused lsort: per partition (512 nodes): (1) LDS degree histogram (batched
// loads, 4/pass); (2) dinv + ovf allocation (local scan, per-partition fixed
// base align8(pbase[p]) + 4096p); (3) scatter src<<7 ints (batched loads);
// (4) self entry + pads = N<<7 (dummy row, dinv[N]=0 -> weight 0 in gather).
__global__ __launch_bounds__(512) void lsort_kernel(const unsigned int* __restrict__ binned,
                                                    const int* __restrict__ pbase,
                                                    float* __restrict__ dinv,
                                                    int* __restrict__ ovfw,
                                                    int* __restrict__ csrw,
                                                    int* __restrict__ ovf, int N) {
    __shared__ int ldeg[512];
    __shared__ int s[512];
    __shared__ int sob[512];
    int t = threadIdx.x, p = blockIdx.x;
    int lo = p << 9;
    ldeg[t] = 0;
    __syncthreads();
    int eBeg = pbase[p], eEnd = pbase[p + 1];
    {
        int j = eBeg + t;
        for (; j + 1536 < eEnd; j += 2048) {   // all 4 indices valid
            unsigned int v0 = binned[j], v1 = binned[j + 512];
            unsigned int v2 = binned[j + 1024], v3 = binned[j + 1536];
            atomicAdd(&ldeg[v0 & 511u], 1);
            atomicAdd(&ldeg[v1 & 511u], 1);
            atomicAdd(&ldeg[v2 & 511u], 1);
            atomicAdd(&ldeg[v3 & 511u], 1);
        }
        for (; j < eEnd; j += 512) atomicAdd(&ldeg[binned[j] & 511u], 1);
    }
    __syncthreads();
    int real = ldeg[t];
    int deg1 = real + 1;
    int ovfUsed = (lo + t < N) ? max(deg1 - 24, 0) : 0;
    int gsl = ((ovfUsed + 7) >> 3) << 3;       // padded ovf slots (multiple of 8)
    s[t] = gsl;
    __syncthreads();
    for (int off = 1; off < 512; off <<= 1) {
        int u = (t >= off) ? s[t - off] : 0;
        __syncthreads();
        s[t] += u;
        __syncthreads();
    }
    int obase = ((eBeg + 7) & ~7) + (p << 12);           // align8(pbase[p]) + 4096p
    int myOvf = obase + (s[t] - gsl);                    // exclusive local scan
    int ow = gsl ? (((myOvf >> 3) << 7) | (gsl >> 3)) : 0;
    if (lo + t < N) {
        dinv[lo + t] = rsqrtf((float)deg1);
        ovfw[lo + t] = ow;
    }
    if (p == 0 && t == 0) dinv[N] = 0.f;                 // dummy row: pad weight 0
    __syncthreads();
    ldeg[t] = 0;                                         // reuse as scatter cursor
    sob[t] = myOvf;
    __syncthreads();
    {
        int j = eBeg + t;
        for (; j + 1536 < eEnd; j += 2048) {
            unsigned int v[4] = {binned[j], binned[j + 512],
                                 binned[j + 1024], binned[j + 1536]};
#pragma unroll
            for (int q = 0; q < 4; ++q) {
                int sr = (int)(v[q] >> 9);
                int dl = (int)(v[q] & 511u);
                int i = atomicAdd(&ldeg[dl], 1);
                int ent = sr << 7;
                if (i < 24) csrw[(size_t)(lo + dl) * 24 + i] = ent;
                else        ovf[sob[dl] + i - 24] = ent;
            }
        }
        for (; j < eEnd; j += 512) {
            unsigned int vv = binned[j];
            int sr = (int)(vv >> 9);
            int dl = (int)(vv & 511u);
            int i = atomicAdd(&ldeg[dl], 1);
            int ent = sr << 7;
            if (i < 24) csrw[(size_t)(lo + dl) * 24 + i] = ent;
            else        ovf[sob[dl] + i - 24] = ent;
        }
    }
    __syncthreads();
    if (lo + t < N) {
        int node = lo + t;
        int dcur = ldeg[t];                              // == real
        int self = node << 7;
        if (dcur < 24) csrw[(size_t)node * 24 + dcur] = self;
        else           ovf[sob[t] + dcur - 24] = self;
        int pad = N << 7;
        for (int k = dcur + 1; k < 24; ++k)
            csrw[(size_t)node * 24 + k] = pad;           // main pads
        int og = (ow & 127) << 3;
        for (int k = max(dcur + 1 - 24, 0); k < og; ++k)
            ovf[sob[t] + k] = pad;                       // ovf pads
    }
}

// MFMA GEMM (layers 2/3, bf16 input): H[N,64](bf16) = X[N,64] @ W[64,64].
// X tile staged through LDS (coalesced), fragments via ds_read_b128.
template <int FIN>
__global__ __launch_bounds__(256) void gemm_mfma_kernel(const unsigned short* __restrict__ Xv,
                                                        const unsigned short* __restrict__ Wt,
                                                        unsigned short* __restrict__ H,
                                                        int N) {
    constexpr int KS = FIN / 32;
    constexpr int LDP = FIN + 8;
    __shared__ unsigned short sX[64 * LDP];
    int tid = threadIdx.x;
    int rowBase = blockIdx.x * 64;

    for (int i = tid * 8; i < 64 * FIN; i += 2048) {
        int r = i / FIN, c = i - r * FIN;
        int gr = min(rowBase + r, N - 1);
        uint4 vv = *(const uint4*)(Xv + (size_t)gr * FIN + c);
        *(uint4*)&sX[r * LDP + c] = vv;
    }
    __syncthreads();

    int wave = tid >> 6;
    int lane = tid & 63;
    int r = lane & 15, g = lane >> 4;
    int node = rowBase + wave * 16 + r;

    bf16x8 afr[4][KS];
#pragma unroll
    for (int m = 0; m < 4; ++m)
#pragma unroll
        for (int s = 0; s < KS; ++s)
            afr[m][s] = *(const bf16x8*)&Wt[(m * 16 + r) * FIN + s * 32 + g * 8];

    f32x4 acc[4];
#pragma unroll
    for (int m = 0; m < 4; ++m) acc[m] = (f32x4){0.f, 0.f, 0.f, 0.f};

#pragma unroll
    for (int s = 0; s < KS; ++s) {
        bf16x8 bfr = *(const bf16x8*)&sX[(wave * 16 + r) * LDP + s * 32 + g * 8];
#pragma unroll
        for (int m = 0; m < 4; ++m)
            acc[m] = __builtin_amdgcn_mfma_f32_16x16x32_bf16(afr[m][s], bfr, acc[m], 0, 0, 0);
    }

    if (node < N) {
#pragma unroll
        for (int m = 0; m < 4; ++m) {
            ushort4 o;
            o.x = f2bf(acc[m][0]); o.y = f2bf(acc[m][1]);
            o.z = f2bf(acc[m][2]); o.w = f2bf(acc[m][3]);
            *(ushort4*)&H[(size_t)node * 64 + m * 16 + g * 4] = o;
        }
    }
}

// Gather step v10: NQ x 8 edges, unguarded. csrw entries are src<<7 ints;
// weight = dinv[src]*di computed here (dinv 400KB, L2-resident; same addr
// across a slot-group's 8 lanes -> broadcast). Pads hit dummy row N, dinv=0.
template <int NQ>
__device__ __forceinline__ void gstep(const int* __restrict__ csrw,
                                      const float* __restrict__ dinv,
                                      const char* __restrict__ hb, float di,
                                      int e, int g, int fo, f32x2 acc[4]) {
    int c[NQ];
#pragma unroll
    for (int q = 0; q < NQ; ++q) c[q] = csrw[e + 8 * q + g];
    float w[NQ];
    uint4 u[NQ];
#pragma unroll
    for (int q = 0; q < NQ; ++q) w[q] = dinv[c[q] >> 7];
#pragma unroll
    for (int q = 0; q < NQ; ++q)
        u[q] = *(const uint4*)(hb + c[q] + fo);
#pragma unroll
    for (int q = 0; q < NQ; ++q) {
        float wq = w[q] * di;
        f32x2 w2;
        w2.x = wq; w2.y = wq;
        acc[0] = __builtin_elementwise_fma(w2, (f32x2){bflo(u[q].x), bfhi(u[q].x)}, acc[0]);
        acc[1] = __builtin_elementwise_fma(w2, (f32x2){bflo(u[q].y), bfhi(u[q].y)}, acc[1]);
        acc[2] = __builtin_elementwise_fma(w2, (f32x2){bflo(u[q].z), bfhi(u[q].z)}, acc[2]);
        acc[3] = __builtin_elementwise_fma(w2, (f32x2){bflo(u[q].w), bfhi(u[q].w)}, acc[3]);
    }
}

// Gather v10: one wave per dst node. lane j: edge-slot g=j>>3, feat f=j&7.
// Fixed-stride CSR: 24 int slots at csrw[node*24]; overflow via packed ovfw.
__global__ __launch_bounds__(256) void gather_kernel(const int* __restrict__ csrw,
                                                     const int* __restrict__ ovf,
                                                     const int* __restrict__ ovfw,
                                                     const float* __restrict__ dinv,
                                                     const unsigned short* __restrict__ h,
                                                     const float* __restrict__ b,
                                                     unsigned short* __restrict__ aggb, int N) {
    int node = (blockIdx.x * 256 + threadIdx.x) >> 6;
    int lane = threadIdx.x & 63;
    if (node >= N) return;
    int g = lane >> 3;
    int f = lane & 7;
    int fo = f * 16;
    float di = dinv[node];

    f32x2 acc[4];
#pragma unroll
    for (int k = 0; k < 4; ++k) acc[k] = (f32x2){0.f, 0.f};

    const char* hb = (const char*)h;
    gstep<3>(csrw, dinv, hb, di, node * 24, g, fo, acc);

    int ow = ovfw[node];
    if (ow) {
        int onb = ow & 127;
        int oe = (ow >> 7) << 3;
        while (onb >= 4) { gstep<4>(ovf, dinv, hb, di, oe, g, fo, acc); oe += 32; onb -= 4; }
        if (onb == 3)      gstep<3>(ovf, dinv, hb, di, oe, g, fo, acc);
        else if (onb == 2) gstep<2>(ovf, dinv, hb, di, oe, g, fo, acc);
        else if (onb == 1) gstep<1>(ovf, dinv, hb, di, oe, g, fo, acc);
    }

    float a[8];
#pragma unroll
    for (int k = 0; k < 4; ++k) { a[2 * k] = acc[k].x; a[2 * k + 1] = acc[k].y; }
#pragma unroll
    for (int k = 0; k < 8; ++k) {
        float v = a[k];
        v += __shfl_xor(v, 8);
        v += __shfl_xor(v, 16);
        v += __shfl_xor(v, 32);
        a[k] = v;
    }
    if (g == 0) {
        float4 bv0 = *(const float4*)&b[f * 8];
        float4 bv1 = *(const float4*)&b[f * 8 + 4];
        float a0 = fmaxf(a[0] + bv0.x, 0.f), a1 = fmaxf(a[1] + bv0.y, 0.f);
        float a2 = fmaxf(a[2] + bv0.z, 0.f), a3 = fmaxf(a[3] + bv0.w, 0.f);
        float a4 = fmaxf(a[4] + bv1.x, 0.f), a5 = fmaxf(a[5] + bv1.y, 0.f);
        float a6 = fmaxf(a[6] + bv1.z, 0.f), a7 = fmaxf(a[7] + bv1.w, 0.f);
        uint4 o;
        o.x = ((unsigned)f2bf(a1) << 16) | f2bf(a0);
        o.y = ((unsigned)f2bf(a3) << 16) | f2bf(a2);
        o.z = ((unsigned)f2bf(a5) << 16) | f2bf(a4);
        o.w = ((unsigned)f2bf(a7) << 16) | f2bf(a6);
        *(uint4*)&aggb[((size_t)node << 6) + f * 8] = o;
    }
}

// Pool v2: one wave per 32 contiguous nodes (lane = col). batch preloaded once
// (coalesced) + __shfl per node; all 32 row loads issued upfront.
__global__ __launch_bounds__(256) void pool_kernel(const unsigned short* __restrict__ hb,
                                                   const int* __restrict__ batch,
                                                   float* __restrict__ sums,
                                                   float* __restrict__ cnts, int N) {
    int lane = threadIdx.x & 63;
    int wid = (blockIdx.x * 256 + threadIdx.x) >> 6;
    int base = wid * 32;
    if (base >= N) return;
    int nn = min(N - base, 32);
    int bl = batch[base + min(lane & 31, nn - 1)];

    float v[32];
#pragma unroll
    for (int j = 0; j < 32; ++j) {
        int node = base + min(j, nn - 1);
        v[j] = bf2f(hb[(size_t)node * 64 + lane]);
    }

    int curg = __shfl(bl, 0);
    float acc = 0.f, cnt = 0.f;
#pragma unroll
    for (int j = 0; j < 32; ++j) {
        if (j < nn) {
            int g = __shfl(bl, j);
            if (g != curg) {
                atomicAdd(&sums[curg * 64 + lane], acc);
                if (lane == 0) atomicAdd(&cnts[curg], cnt);
                acc = 0.f; cnt = 0.f; curg = g;
            }
            acc += v[j]; cnt += 1.f;
        }
    }
    atomicAdd(&sums[curg * 64 + lane], acc);
    if (lane == 0) atomicAdd(&cnts[curg], cnt);
}

// One thread per graph: pooled = sums/cnt, logits = pooled @ Wl + bl, softmax.
__global__ void final_kernel(const float* __restrict__ sums, const float* __restrict__ cnts,
                             const float* __restrict__ Wl, const float* __restrict__ bl,
                             float* __restrict__ out, int G) {
    int g = blockIdx.x * blockDim.x + threadIdx.x;
    if (g >= G) return;
    float inv = 1.0f / fmaxf(cnts[g], 1.0f);
    float logits[10];
#pragma unroll
    for (int k = 0; k < 10; ++k) logits[k] = bl[k];
    for (int c = 0; c < 64; ++c) {
        float p = sums[g * 64 + c] * inv;
#pragma unroll
        for (int k = 0; k < 10; ++k) logits[k] = fmaf(p, Wl[c * 10 + k], logits[k]);
    }
    float m = logits[0];
#pragma unroll
    for (int k = 1; k < 10; ++k) m = fmaxf(m, logits[k]);
    float se = 0.f;
#pragma unroll
    for (int k = 0; k < 10; ++k) { logits[k] = expf(logits[k] - m); se += logits[k]; }
    float is = 1.0f / se;
#pragma unroll
    for (int k = 0; k < 10; ++k) out[g * 10 + k] = logits[k] * is;
}

extern "C" void kernel_launch(void* const* d_in, const int* in_sizes, int n_in,
                              void* d_out, int out_size, void* d_ws, size_t ws_size,
                              hipStream_t stream) {
    const float* x    = (const float*)d_in[0];
    const int* edges  = (const int*)d_in[1];
    const int* batch  = (const int*)d_in[2];
    const float* W1   = (const float*)d_in[3];
    const float* b1   = (const float*)d_in[4];
    const float* W2   = (const float*)d_in[5];
    const float* b2   = (const float*)d_in[6];
    const float* W3   = (const float*)d_in[7];
    const float* b3   = (const float*)d_in[8];
    const float* Wl   = (const float*)d_in[9];
    const float* bl   = (const float*)d_in[10];

    const int N = in_sizes[0] / 128;   // 100000
    const int E = in_sizes[1] / 2;     // 1600000
    const int G = out_size / 10;       // 64
    const int* src = edges;
    const int* dst = edges + E;

    // workspace layout (floats). h row N (pad dummy) reads into aggb start --
    // harmless (weight 0).
    float* ws     = (float*)d_ws;
    unsigned short* h = (unsigned short*)ws;              // N*64 bf16 = N*32 floats
    unsigned short* aggb = (unsigned short*)(ws + (size_t)N * 32);  // N*64 bf16
    unsigned int* binned = (unsigned int*)(ws + (size_t)N * 32);    // E uint, ALIASES aggb
                                                          // (dead until gather1)
    size_t o = (size_t)N * 64;
    int*   csrw   = (int*)(ws + o);    o += (size_t)24 * N;           // 24N ints (src<<7)
    int*   ovf    = (int*)(ws + o);    o += (size_t)E + 4096 * 256 + 8;
    float* dinv   = ws + o;            o += N + 1;        // +1: dinv[N]=0 dummy
    int*   ovfw   = (int*)(ws + o);    o += N;
    int*   counts = (int*)(ws + o);    o += 256 * 256;    // CHUNK-MAJOR [b][t]
    int*   offs   = (int*)(ws + o);    o += 256 * 256;
    int*   pbase  = (int*)(ws + o);    o += 257;
    float* sums   = ws + o;            o += (size_t)G * 64;
    float* cnts   = ws + o;            o += G;
    unsigned short* Wt1 = (unsigned short*)(ws + o);      // 64*128 + 2*64*64 shorts
    unsigned short* Wt2 = Wt1 + 64 * 128;
    unsigned short* Wt3 = Wt2 + 64 * 64;

    const int gemmGrid = (N + 63) / 64;
    const int gatherGrid = (N + 3) / 4;
    const int poolGrid = ((N + 31) / 32 + 3) / 4;
    const int P = (N + 511) >> 9;                 // 196 partitions of 512 nodes
    const int C = (((E + 255) / 256) + 7) & ~7;   // edges per chunk, multiple of 8

    // sort -> fixed-stride CSR (24 int slots/node, src<<7) + overflow region
    hist_kernel<<<260, 256, 0, stream>>>(dst, counts, E, P, C,
                                         W1, W2, W3, Wt1, Wt2, Wt3, sums, G);
    pscan_kernel<<<1, 256, 0, stream>>>(counts, pbase, P);
    offs_kernel<<<P, 256, 0, stream>>>(counts, pbase, offs);
    bin_kernel<<<256, 256, 0, stream>>>(src, dst, offs, binned, E, P, C);
    gemm1_kernel<<<gemmGrid, 256, 0, stream>>>(x, Wt1, h, N);
    lsort_kernel<<<P, 512, 0, stream>>>(binned, pbase, dinv, ovfw, csrw, ovf, N);

    // layer 1 gather
    gather_kernel<<<gatherGrid, 256, 0, stream>>>(csrw, ovf, ovfw, dinv, h, b1, aggb, N);

    // layer 2
    gemm_mfma_kernel<64><<<gemmGrid, 256, 0, stream>>>(aggb, Wt2, h, N);
    gather_kernel<<<gatherGrid, 256, 0, stream>>>(csrw, ovf, ovfw, dinv, h, b2, aggb, N);

    // layer 3
    gemm_mfma_kernel<64><<<gemmGrid, 256, 0, stream>>>(aggb, Wt3, h, N);
    gather_kernel<<<gatherGrid, 256, 0, stream>>>(csrw, ovf, ovfw, dinv, h, b3, aggb, N);

    // mean-pool per graph + head + softmax (sums/cnts zeroed in hist's extra block)
    pool_kernel<<<poolGrid, 256, 0, stream>>>(aggb, batch, sums, cnts, N);
    final_kernel<<<1, 64, 0, stream>>>(sums, cnts, Wl, bl, (float*)d_out, G);
}